// Round 9
// baseline (415.379 us; speedup 1.0000x reference)
//
#include <hip/hip_runtime.h>
#include <hip/hip_bf16.h>
#include <math.h>

typedef unsigned short u16;
typedef unsigned int u32;

typedef __bf16 bf16x8 __attribute__((ext_vector_type(8)));
typedef float f32x4 __attribute__((ext_vector_type(4)));
typedef u32 u32x4 __attribute__((ext_vector_type(4)));

union U8 { uint4 u; u16 s[8]; };

__device__ __forceinline__ float b2f(u16 x) {
    u32 y = ((u32)x) << 16;
    return __builtin_bit_cast(float, y);
}
__device__ __forceinline__ u16 f2b(float f) {
    u32 x = __builtin_bit_cast(u32, f);
    u32 r = x + 0x7fffu + ((x >> 16) & 1u);
    return (u16)(r >> 16);
}
// pack 8 fp32 -> 8 bf16 (one uint4)
__device__ __forceinline__ uint4 cvt8(float4 a, float4 b) {
    U8 o;
    o.s[0] = f2b(a.x); o.s[1] = f2b(a.y); o.s[2] = f2b(a.z); o.s[3] = f2b(a.w);
    o.s[4] = f2b(b.x); o.s[5] = f2b(b.y); o.s[6] = f2b(b.z); o.s[7] = f2b(b.w);
    return o.u;
}

// nontemporal stores (gfx950 'nt' flag): epilogue/bulk streams must not evict
// L2-resident operand panels (round-9 theory: gemm8p<2> was L2-thrash-bound).
__device__ __forceinline__ void nt_store16(void* p, uint4 v) {
    __builtin_nontemporal_store(__builtin_bit_cast(u32x4, v), (u32x4*)p);
}
__device__ __forceinline__ void nt_store_u16(u16* p, u16 v) {
    __builtin_nontemporal_store(v, p);
}
__device__ __forceinline__ void nt_store_u32(u32* p, u32 v) {
    __builtin_nontemporal_store(v, p);
}
__device__ __forceinline__ void nt_store_f32(float* p, float v) {
    __builtin_nontemporal_store(v, p);
}

// async global->LDS, 16 B per lane; LDS dest = wave-uniform base + lane*16
__device__ __forceinline__ void gload16(const u16* g, const u16* l) {
    __builtin_amdgcn_global_load_lds(
        (const __attribute__((address_space(1))) void*)g,
        (__attribute__((address_space(3))) void*)l, 16, 0, 0);
}

// ---------------- small kernels ----------------

__global__ void __launch_bounds__(64) zero_ss(float* ss) {
    if (threadIdx.x < 2) ss[threadIdx.x] = 0.f;
}

// ---------------- fused prep kernel ----------------
// One dispatch: twvh + sumsq x2 + cvt q + cvt Wq (+ cvt v). blockIdx.x ranges:
//   [0, 1536)      twvh v2: wvh[h][c][k] = bf16(hm[h,k]*Wv[k,c]), 64k x 32c tile,
//                  k-PAIRED u32 stores (wave = 128 B contiguous, half the instrs
//                  of the old scalar-u16 version), nontemporal.
//   [1536, 2048)   sumsq: ss[0] += |Wv|^2 (256 blks), ss[1] += |Wq|^2 (256)
//   [2048, 3072)   cvt q  -> qb   (2,097,152 floats, exact)
//   [3072, 4608)   cvt Wq -> wqb  (3,145,728 floats, exact)
//   [4608, 6656)   cvt v  -> vb   (16,777,216 floats, 4-iter stride) [fullfat]
__global__ void __launch_bounds__(256)
prep_k(const float* __restrict__ Wv, const float* __restrict__ Wq,
       const float* __restrict__ q, const float* __restrict__ v,
       const float* __restrict__ hm, float* __restrict__ ss,
       u16* __restrict__ wvh, u16* __restrict__ qb,
       u16* __restrict__ wqb, u16* __restrict__ vb) {
    const int bid = blockIdx.x, tid = threadIdx.x;
    if (bid < 1536) {
        // ---- twvh v2: 64k x 32c tile, transpose + 8-head scale ----
        __shared__ float t[64][33];
        int bx = bid & 31, by = bid >> 5;        // 32 c-tiles x 48 k-tiles
        int cx0 = bx * 32, ky0 = by * 64;
        int tx = tid & 31, ty = tid >> 5;
#pragma unroll
        for (int j = ty; j < 64; j += 8)
            t[j][tx] = Wv[(size_t)(ky0 + j) * 1024 + cx0 + tx];
        // hv for this thread's k-pair (2tx, 2tx+1)
        int k0 = ky0 + 2 * tx;
        float hv0[8], hv1[8];
#pragma unroll
        for (int h = 0; h < 8; h++) {
            hv0[h] = hm[(size_t)h * 3072 + k0];
            hv1[h] = hm[(size_t)h * 3072 + k0 + 1];
        }
        __syncthreads();
#pragma unroll
        for (int j = ty; j < 32; j += 8) {
            float w0 = t[2 * tx][j], w1 = t[2 * tx + 1][j];
            int c = cx0 + j;
#pragma unroll
            for (int h = 0; h < 8; h++) {
                u32 val = (u32)f2b(hv0[h] * w0) | ((u32)f2b(hv1[h] * w1) << 16);
                nt_store_u32((u32*)(wvh + (size_t)h * 3145728 + (size_t)c * 3072 + k0), val);
            }
        }
    } else if (bid < 2048) {
        // ---- sumsq of Wv (sub<256) / Wq ----
        int sub = bid - 1536;
        const float* W = (sub < 256) ? Wv : Wq;
        int lb = sub & 255;
        float acc = 0.f;
        const size_t stride = (size_t)256 * 256 * 8;
        for (size_t i = ((size_t)lb * 256 + tid) * 8; i < (size_t)(3072 * 1024); i += stride) {
            float4 a = *(const float4*)(W + i);
            float4 b = *(const float4*)(W + i + 4);
            acc += a.x * a.x + a.y * a.y + a.z * a.z + a.w * a.w;
            acc += b.x * b.x + b.y * b.y + b.z * b.z + b.w * b.w;
        }
#pragma unroll
        for (int o = 32; o > 0; o >>= 1) acc += __shfl_down(acc, o, 64);
        __shared__ float red[4];
        int lane = tid & 63, w6 = tid >> 6;
        if (lane == 0) red[w6] = acc;
        __syncthreads();
        if (tid == 0) atomicAdd(&ss[sub >> 8], red[0] + red[1] + red[2] + red[3]);
    } else if (bid < 3072) {
        // ---- cvt q -> qb (exact cover) ----
        size_t i = ((size_t)(bid - 2048) * 256 + tid) * 8;
        float4 a = *(const float4*)(q + i);
        float4 b = *(const float4*)(q + i + 4);
        nt_store16(qb + i, cvt8(a, b));
    } else if (bid < 4608) {
        // ---- cvt Wq -> wqb (exact cover) ----
        size_t i = ((size_t)(bid - 3072) * 256 + tid) * 8;
        float4 a = *(const float4*)(Wq + i);
        float4 b = *(const float4*)(Wq + i + 4);
        nt_store16(wqb + i, cvt8(a, b));
    } else {
        // ---- cvt v -> vb (grid-stride, 4 iters) ----
        const size_t stride = (size_t)2048 * 256 * 8;
        for (size_t i = ((size_t)(bid - 4608) * 256 + tid) * 8; i < (size_t)16777216; i += stride) {
            float4 a = *(const float4*)(v + i);
            float4 b = *(const float4*)(v + i + 4);
            nt_store16(vb + i, cvt8(a, b));
        }
    }
}

// cb[o] = sum_k bv[k]*hm[h,k]*q_[b*128+d, k], o = b*1024 + h*128 + d.
// 256 blocks; 4 threads per output (K/4 each); shfl_xor quad-reduce; no atomics.
__global__ void __launch_bounds__(256) const_k(const u16* __restrict__ qbuf,
                                               const float* __restrict__ bv,
                                               const float* __restrict__ hm,
                                               float* __restrict__ cb) {
    int o = blockIdx.x * 64 + (threadIdx.x >> 2);   // 0..16383
    int qt = threadIdx.x & 3;                        // K quarter
    int b = o >> 10, hd = o & 1023, h = hd >> 7, d = hd & 127;
    const u16* qr = qbuf + ((size_t)b * 128 + d) * 3072 + qt * 768;
    const float* hr = hm + (size_t)h * 3072 + qt * 768;
    const float* br = bv + qt * 768;
    float acc = 0.f;
    for (int k = 0; k < 768; k += 8) {
        U8 uq; uq.u = *(const uint4*)(qr + k);
        float4 h0 = *(const float4*)(hr + k);
        float4 h1 = *(const float4*)(hr + k + 4);
        float4 b0 = *(const float4*)(br + k);
        float4 b1 = *(const float4*)(br + k + 4);
        acc += b2f(uq.s[0]) * h0.x * b0.x + b2f(uq.s[1]) * h0.y * b0.y +
               b2f(uq.s[2]) * h0.z * b0.z + b2f(uq.s[3]) * h0.w * b0.w +
               b2f(uq.s[4]) * h1.x * b1.x + b2f(uq.s[5]) * h1.y * b1.y +
               b2f(uq.s[6]) * h1.z * b1.z + b2f(uq.s[7]) * h1.w * b1.w;
    }
    acc += __shfl_xor(acc, 1, 64);
    acc += __shfl_xor(acc, 2, 64);
    if (qt == 0) cb[o] = acc;
}

// ---------------- legacy 128x128 BT-GEMM (2-phase, __syncthreads) ----------------
// kept for EPI 0 (small N, more blocks) and the fp32-A fallback of EPI 2.
// EPI 0: bijective XCD chunking -- grid (24,16), 48 blocks/XCD as 6bx x 8by;
// per-XCD operand footprint 3.5 MB < 4 MB L2.
template <int EPI, bool A_BF16>
__global__ void __launch_bounds__(256)
gemm_bt(const void* __restrict__ Ap, const u16* __restrict__ Bp, void* __restrict__ C,
        const float* __restrict__ ss, int ss_idx, const float* __restrict__ g,
        const float* __restrict__ bias, const float* __restrict__ cb,
        const float* __restrict__ hbias, int kdim, size_t abatch, size_t bbatch) {
    constexpr int BK = 32;
    __shared__ __align__(16) u16 sA[2][128 * BK];
    __shared__ __align__(16) u16 sB[2][128 * BK];

    const int tid = threadIdx.x;
    const int lane = tid & 63, wv = tid >> 6;
    const int wm = (wv & 1) * 64, wn = (wv >> 1) * 64;
    const int lr = lane & 15, quad = lane >> 4;
    const int z = blockIdx.z;

    int bxx, byy;
    if constexpr (EPI == 0) {
        int lin = blockIdx.y * 24 + blockIdx.x;     // grid (24,16)
        int xcd = lin & 7, i = lin >> 3;            // i in 0..47
        bxx = (xcd & 3) * 6 + i % 6;
        byy = (xcd >> 2) * 8 + i / 6;
    } else {
        bxx = blockIdx.x; byy = blockIdx.y;
    }
    const int arow0 = byy * 128;
    const int bcol0 = bxx * 128;

    const size_t aoff = (size_t)z * abatch;
    const size_t boff = (size_t)z * bbatch;

    const int srow = 16 * wv + (lane >> 2);
    const int qcg  = (lane & 3) ^ ((lane >> 3) & 3);
    const int lb0  = wv * 512;
    const int lb1  = lb0 + 2048;

    const u16* gB0 = Bp + boff + (size_t)(bcol0 + srow) * kdim + qcg * 8;
    const u16* gB1 = gB0 + (size_t)64 * kdim;

    const int r0 = tid >> 2, c0 = (tid & 3) * 8;
    const int w0 = r0 * 32 + (((tid & 3) ^ ((tid >> 3) & 3)) * 8);
    const int w1 = w0 + 2048;

    const u16* gA0 = nullptr; const u16* gA1 = nullptr;
    const float* fA0 = nullptr; const float* fA1 = nullptr;
    if constexpr (A_BF16) {
        gA0 = (const u16*)Ap + aoff + (size_t)(arow0 + srow) * kdim + qcg * 8;
        gA1 = gA0 + (size_t)64 * kdim;
    } else {
        fA0 = (const float*)Ap + aoff + (size_t)(arow0 + r0) * kdim + c0;
        fA1 = fA0 + (size_t)64 * kdim;
    }

    const int rsw = (quad ^ ((lr >> 1) & 3)) * 8;

    if constexpr (A_BF16) {
        gload16(gA0, sA[0] + lb0);
        gload16(gA1, sA[0] + lb1);
        gA0 += BK; gA1 += BK;
    } else {
        float4 x0 = *(const float4*)fA0, x1 = *(const float4*)(fA0 + 4);
        float4 y0 = *(const float4*)fA1, y1 = *(const float4*)(fA1 + 4);
        *(uint4*)(sA[0] + w0) = cvt8(x0, x1);
        *(uint4*)(sA[0] + w1) = cvt8(y0, y1);
        fA0 += BK; fA1 += BK;
    }
    gload16(gB0, sB[0] + lb0);
    gload16(gB1, sB[0] + lb1);
    gB0 += BK; gB1 += BK;

    f32x4 acc[4][4];
#pragma unroll
    for (int im = 0; im < 4; im++)
#pragma unroll
        for (int in = 0; in < 4; in++) acc[im][in] = (f32x4){0.f, 0.f, 0.f, 0.f};

    __syncthreads();

    int p = 0;
    for (int kt = 0; kt < kdim; kt += BK) {
        const bool more = (kt + BK < kdim);

        float4 ax0, ax1, ay0, ay1;
        if (more) {
            if constexpr (A_BF16) {
                gload16(gA0, sA[p ^ 1] + lb0);
                gload16(gA1, sA[p ^ 1] + lb1);
                gA0 += BK; gA1 += BK;
            } else {
                ax0 = *(const float4*)fA0; ax1 = *(const float4*)(fA0 + 4);
                ay0 = *(const float4*)fA1; ay1 = *(const float4*)(fA1 + 4);
                fA0 += BK; fA1 += BK;
            }
            gload16(gB0, sB[p ^ 1] + lb0);
            gload16(gB1, sB[p ^ 1] + lb1);
            gB0 += BK; gB1 += BK;
        }

        const u16* sAp = sA[p];
        const u16* sBp = sB[p];
        bf16x8 af[4], bfr[4];
#pragma unroll
        for (int im = 0; im < 4; im++)
            af[im] = *(const bf16x8*)(sAp + (wm + im * 16 + lr) * 32 + rsw);
#pragma unroll
        for (int in = 0; in < 4; in++)
            bfr[in] = *(const bf16x8*)(sBp + (wn + in * 16 + lr) * 32 + rsw);
#pragma unroll
        for (int im = 0; im < 4; im++)
#pragma unroll
            for (int in = 0; in < 4; in++)
                acc[im][in] = __builtin_amdgcn_mfma_f32_16x16x32_bf16(af[im], bfr[in], acc[im][in], 0, 0, 0);

        if (more) {
            if constexpr (!A_BF16) {
                u16* dA = sA[p ^ 1];
                *(uint4*)(dA + w0) = cvt8(ax0, ax1);
                *(uint4*)(dA + w1) = cvt8(ay0, ay1);
            }
        }
        __syncthreads();
        p ^= 1;
    }

    float scale = 1.f;
    if constexpr (EPI == 0 || EPI == 2) scale = g[0] / sqrtf(ss[ss_idx]);

#pragma unroll
    for (int im = 0; im < 4; im++) {
#pragma unroll
        for (int in = 0; in < 4; in++) {
#pragma unroll
            for (int reg = 0; reg < 4; reg++) {
                int gr = arow0 + wm + im * 16 + quad * 4 + reg;
                int gc = bcol0 + wn + in * 16 + lr;
                float val = acc[im][in][reg];
                if constexpr (EPI == 0) {
                    nt_store_u16((u16*)C + (size_t)gr * 3072 + gc, f2b(val * scale + bias[gc]));
                } else if constexpr (EPI == 1) {
                    size_t idx = (((size_t)(gr >> 7) * 8 + (gc >> 10)) * 128 + (gr & 127)) * 1024
                               + (gc & 1023);
                    nt_store_u16((u16*)C + idx, f2b(val));
                } else {
                    int h = gc >> 7, d = gc & 127;
                    float o = val * scale + cb[(size_t)z * 1024 + gc] + hbias[h];
                    nt_store_f32((float*)C + (((size_t)z * 8 + h) * 1024 + gr) * 128 + d, o);
                }
            }
        }
    }
}

// ---------------- 256x256 BT-GEMM, single-barrier-per-tile free-running pipeline --------
// (hot loop unchanged from round 6 -- proven 85 us / MfmaUtil 52%)
// EPI 2: z-locality XCD chunking (XCD k owns z in {k, k+8}).
// Round 9: epilogue stores nontemporal -- the 67 MB (EPI2) / 33 MB (EPI1) write
// streams were evicting L2-resident operand panels.
template <int EPI>
__global__ void __launch_bounds__(512, 2)
gemm8p(const u16* __restrict__ Ap, const u16* __restrict__ Bp, void* __restrict__ C,
       const float* __restrict__ ss, const float* __restrict__ g,
       const float* __restrict__ cb, const float* __restrict__ hbias,
       int kdim, size_t abatch, size_t bbatch) {
    __shared__ __align__(16) u16 sAb[2][256 * 64];
    __shared__ __align__(16) u16 sBb[2][256 * 64];

    const int tid = threadIdx.x;
    const int lane = tid & 63, wv = tid >> 6;
    const int wm = (wv & 1) * 128;            // M warp offset (2 warps)
    const int wn = (wv >> 1) * 64;            // N warp offset (4 warps)
    const int lr = lane & 15, quad = lane >> 4;

    int bx, by, z;
    if constexpr (EPI == 1) {
        // T1 chunked XCD swizzle: XCD k owns bx in [4k,4k+4), by 0..7
        int orig = blockIdx.y * 32 + blockIdx.x;       // gridDim = (32,8)
        int xcd = orig & 7, idx = orig >> 3;
        bx = (xcd << 2) | (idx & 3);
        by = idx >> 2;
        z = 0;
    } else {
        // z-locality: grid (4,4,16) -> XCD k runs z=k then z=k+8
        int lin = (blockIdx.z * 4 + blockIdx.y) * 4 + blockIdx.x;  // 0..255
        int xcd = lin & 7, i = lin >> 3;                           // i in 0..31
        z = xcd + 8 * (i >> 4);
        int sub = i & 15;
        bx = sub & 3; by = sub >> 2;
    }
    const int arow0 = by * 256, bcol0 = bx * 256;

    const size_t aoff = (size_t)z * abatch, boff = (size_t)z * bbatch;

    // staging lane map: call = 64 rows x 64 cols (8KB); thread covers row tid>>3,
    // 16B-group tid&7, fetching pre-swizzled global group (tid&7) ^ (row&7)
    const int sg = (tid & 7) ^ ((tid >> 3) & 7);
    const u16* gA = Ap + aoff + (size_t)(arow0 + (tid >> 3)) * kdim + sg * 8;
    const u16* gB = Bp + boff + (size_t)(bcol0 + (tid >> 3)) * kdim + sg * 8;
    const size_t ldk64 = (size_t)64 * kdim;    // 64-row call stride (elements)
    const int ldst = wv * 512;                 // wave's u16 offset within a call

    // frag read bases (u16): row*64 + slot*8, slot = quad ^ (row&7); ks=1 -> ^32
    const int slot = (quad ^ (lane & 7)) * 8;
    const int rbA = (wm + lr) * 64 + slot;
    const int rbB = (wn + lr) * 64 + slot;

    f32x4 acc[8][4];
#pragma unroll
    for (int im = 0; im < 8; im++)
#pragma unroll
        for (int in = 0; in < 4; in++) acc[im][in] = (f32x4){0.f, 0.f, 0.f, 0.f};

    // ---- prologue: stage K-tile 0 into buf 0, full drain ----
    gload16(gB + 0 * ldk64, sBb[0] + 0 * 4096 + ldst);
    gload16(gB + 1 * ldk64, sBb[0] + 1 * 4096 + ldst);
    gload16(gB + 2 * ldk64, sBb[0] + 2 * 4096 + ldst);
    gload16(gB + 3 * ldk64, sBb[0] + 3 * 4096 + ldst);
    gload16(gA + 0 * ldk64, sAb[0] + 0 * 4096 + ldst);
    gload16(gA + 1 * ldk64, sAb[0] + 1 * 4096 + ldst);
    gload16(gA + 2 * ldk64, sAb[0] + 2 * 4096 + ldst);
    gload16(gA + 3 * ldk64, sAb[0] + 3 * 4096 + ldst);
    gA += 64; gB += 64;                        // -> K-tile 1 columns
    asm volatile("s_waitcnt vmcnt(0)" ::: "memory");
    __builtin_amdgcn_s_barrier();

    const u16* sAd = sAb[0];
    const u16* sBd = sBb[0];
    u16* dA = (u16*)sAb[1];
    u16* dB = (u16*)sBb[1];

    bf16x8 af[4], bfr[4], af1[4], af2[4], bf2[4], af3[4];
    // Q0 frags for tile 0
#pragma unroll
    for (int n = 0; n < 4; n++) bfr[n] = *(const bf16x8*)(sBd + rbB + n * 1024);
#pragma unroll
    for (int j = 0; j < 4; j++) af[j] = *(const bf16x8*)(sAd + rbA + j * 1024);

    const int NT = kdim >> 6;
    for (int t = 0; t < NT; ++t) {
        const bool stg = (t + 1 < NT);

        // stage next tile -> D (burst, max slack before the tile-end vmcnt(0))
        if (stg) {
            gload16(gB + 0 * ldk64, dB + 0 * 4096 + ldst);
            gload16(gB + 1 * ldk64, dB + 1 * 4096 + ldst);
            gload16(gB + 2 * ldk64, dB + 2 * 4096 + ldst);
            gload16(gB + 3 * ldk64, dB + 3 * 4096 + ldst);
            gload16(gA + 0 * ldk64, dA + 0 * 4096 + ldst);
            gload16(gA + 1 * ldk64, dA + 1 * 4096 + ldst);
            gload16(gA + 2 * ldk64, dA + 2 * 4096 + ldst);
            gload16(gA + 3 * ldk64, dA + 3 * 4096 + ldst);
        }

        // ---- read Q1, MFMA Q0 ----
#pragma unroll
        for (int j = 0; j < 4; j++) af1[j] = *(const bf16x8*)(sAd + rbA + (4 + j) * 1024);
        __builtin_amdgcn_s_setprio(1);
#pragma unroll
        for (int j = 0; j < 4; j++)
#pragma unroll
            for (int n = 0; n < 4; n++)
                acc[j][n] = __builtin_amdgcn_mfma_f32_16x16x32_bf16(af[j], bfr[n], acc[j][n], 0, 0, 0);
        __builtin_amdgcn_s_setprio(0);

        // ---- read Q2, MFMA Q1 ----
#pragma unroll
        for (int n = 0; n < 4; n++) bf2[n] = *(const bf16x8*)(sBd + (rbB ^ 32) + n * 1024);
#pragma unroll
        for (int j = 0; j < 4; j++) af2[j] = *(const bf16x8*)(sAd + (rbA ^ 32) + j * 1024);
        __builtin_amdgcn_s_setprio(1);
#pragma unroll
        for (int j = 0; j < 4; j++)
#pragma unroll
            for (int n = 0; n < 4; n++)
                acc[4 + j][n] = __builtin_amdgcn_mfma_f32_16x16x32_bf16(af1[j], bfr[n], acc[4 + j][n], 0, 0, 0);
        __builtin_amdgcn_s_setprio(0);

        // ---- read Q3, MFMA Q2 ----
#pragma unroll
        for (int j = 0; j < 4; j++) af3[j] = *(const bf16x8*)(sAd + (rbA ^ 32) + (4 + j) * 1024);
        __builtin_amdgcn_s_setprio(1);
#pragma unroll
        for (int j = 0; j < 4; j++)
#pragma unroll
            for (int n = 0; n < 4; n++)
                acc[j][n] = __builtin_amdgcn_mfma_f32_16x16x32_bf16(af2[j], bf2[n], acc[j][n], 0, 0, 0);
        __builtin_amdgcn_s_setprio(0);

        // ---- tile-end sync (the only barrier) ----
        asm volatile("s_waitcnt vmcnt(0)" ::: "memory");   // D fully staged
        asm volatile("s_waitcnt lgkmcnt(0)" ::: "memory"); // my reads of R done
        __builtin_amdgcn_s_barrier();

        // ---- read next tile's Q0 from D, MFMA Q3 ----
        if (stg) {
#pragma unroll
            for (int n = 0; n < 4; n++) bfr[n] = *(const bf16x8*)(dB + rbB + n * 1024);
#pragma unroll
            for (int j = 0; j < 4; j++) af[j] = *(const bf16x8*)(dA + rbA + j * 1024);
        }
        __builtin_amdgcn_s_setprio(1);
#pragma unroll
        for (int j = 0; j < 4; j++)
#pragma unroll
            for (int n = 0; n < 4; n++)
                acc[4 + j][n] = __builtin_amdgcn_mfma_f32_16x16x32_bf16(af3[j], bf2[n], acc[4 + j][n], 0, 0, 0);
        __builtin_amdgcn_s_setprio(0);

        // swap dbufs, advance K
        const u16* tp = sAd; sAd = dA; dA = (u16*)tp;
        tp = sBd; sBd = dB; dB = (u16*)tp;
        gA += 64; gB += 64;
    }

    // ---- epilogue (nontemporal stores) ----
    float scale = 1.f;
    if constexpr (EPI == 2) scale = g[0] / sqrtf(ss[0]);

#pragma unroll
    for (int im = 0; im < 8; im++) {
#pragma unroll
        for (int in = 0; in < 4; in++) {
#pragma unroll
            for (int reg = 0; reg < 4; reg++) {
                int gr = arow0 + wm + im * 16 + quad * 4 + reg;  // row (M)
                int gc = bcol0 + wn + in * 16 + lr;              // col (N)
                float val = acc[im][in][reg];
                if constexpr (EPI == 1) {
                    // gr = b*128+d (M=2048), gc = h*1024+c (N=8192) -> tbuf[b][h][d][c]
                    size_t idx = (((size_t)(gr >> 7) * 8 + (gc >> 10)) * 128 + (gr & 127)) * 1024
                               + (gc & 1023);
                    nt_store_u16((u16*)C + idx, f2b(val));
                } else {
                    int h = gc >> 7, d = gc & 127;
                    float o = val * scale + cb[(size_t)z * 1024 + gc] + hbias[h];
                    nt_store_f32((float*)C + (((size_t)z * 8 + h) * 1024 + gr) * 128 + d, o);
                }
            }
        }
    }
}

// ---------------- launch ----------------

extern "C" void kernel_launch(void* const* d_in, const int* in_sizes, int n_in,
                              void* d_out, int out_size, void* d_ws, size_t ws_size,
                              hipStream_t stream) {
    (void)in_sizes; (void)n_in; (void)out_size;
    const float* v  = (const float*)d_in[0];   // (16,1024,1024) fp32
    const float* q  = (const float*)d_in[1];   // (16,128,1024)  fp32
    const float* Wv = (const float*)d_in[2];   // (3072,1024)    fp32
    const float* gv = (const float*)d_in[3];
    const float* bv = (const float*)d_in[4];   // (3072)
    const float* Wq = (const float*)d_in[5];   // (3072,1024)
    const float* gq = (const float*)d_in[6];
    const float* bq = (const float*)d_in[7];   // (3072)
    const float* hm = (const float*)d_in[8];   // (8,3072)
    const float* hb = (const float*)d_in[9];   // (8)
    float* out = (float*)d_out;                // fp32 output (16,8,1024,128) = 67 MB

    // workspace layout (floor 46.2 MB; +33.5 MB vb if available)
    char* ws = (char*)d_ws;
    float* ss   = (float*)ws;                          // 256 B
    float* cb   = (float*)(ws + 256);                  // 64 KB
    u16*   qbuf = (u16*)(ws + 256 + 65536);            // 2048*3072 bf16 = 12 MB
    u16*   tbuf = (u16*)(ws + 256 + 65536 + 12582912); // 16*8*128*1024 bf16 = 33.5 MB
    u16*   vb   = (u16*)(ws + 256 + 65536 + 12582912 + 33554432);  // optional 33.5 MB
    const size_t need_vb = 256 + 65536 + 12582912 + 33554432 + 33554432;  // ~80.2 MB
    const bool fullfat = (ws_size >= need_vb);

    // scratch in d_out (67.1 MB), all dead before the final gemm writes out:
    //   wvh 8*1024*3072 bf16 = 50.33 MB | qb 2048*1024 bf16 = 4.19 MB | wqb 3072*1024 bf16 = 6.29 MB
    u16* wvh = (u16*)d_out;
    u16* qb  = (u16*)((char*)d_out + 50331648);
    u16* wqb = (u16*)((char*)d_out + 54525952);   // ends at 60.8 MB < 67.1 MB

    zero_ss<<<1, 64, 0, stream>>>(ss);

    // fused prep: twvh + sumsq + cvt q + cvt Wq (+ cvt v when fullfat)
    prep_k<<<fullfat ? 6656 : 4608, 256, 0, stream>>>(
        Wv, Wq, q, v, hm, ss, wvh, qb, wqb, vb);

    // q_ = q * wn(Wq)^T + bq   (2048 x 3072)
    gemm_bt<0, true><<<dim3(24, 16, 1), 256, 0, stream>>>(
        qb, wqb, qbuf, ss, 1, gq, bq, nullptr, nullptr, 1024, 0, 0);

    // cb[b,hd] = sum_k bv*hm*q_
    const_k<<<256, 256, 0, stream>>>(qbuf, bv, hm, cb);

    // T[b,h,d,c] = sum_k q_[b,d,k] * wvh[h,c,k]  -- ONE GEMM: M=2048, N=8192, K=3072
    gemm8p<1><<<dim3(32, 8, 1), 512, 0, stream>>>(
        qbuf, wvh, tbuf, nullptr, nullptr, nullptr, nullptr, 3072, 0, 0);

    // logits[b,h,n,d] = scale_v * sum_c v[b,n,c]*T[b,hd,c] + cb[b,hd] + hbias[h]
    if (fullfat) {
        gemm8p<2><<<dim3(4, 4, 16), 512, 0, stream>>>(
            vb, tbuf, out, ss, gv, cb, hb, 1024, 1048576, 1048576);
    } else {
        gemm_bt<2, false><<<dim3(8, 8, 16), 256, 0, stream>>>(
            v, tbuf, out, ss, 0, gv, nullptr, cb, hb, 1024, 1048576, 1048576);
    }
}

// Round 10
// 364.060 us; speedup vs baseline: 1.1410x; 1.1410x over previous
//
#include <hip/hip_runtime.h>
#include <hip/hip_bf16.h>
#include <math.h>

typedef unsigned short u16;
typedef unsigned int u32;

typedef __bf16 bf16x8 __attribute__((ext_vector_type(8)));
typedef float f32x4 __attribute__((ext_vector_type(4)));

union U8 { uint4 u; u16 s[8]; };

__device__ __forceinline__ float b2f(u16 x) {
    u32 y = ((u32)x) << 16;
    return __builtin_bit_cast(float, y);
}
__device__ __forceinline__ u16 f2b(float f) {
    u32 x = __builtin_bit_cast(u32, f);
    u32 r = x + 0x7fffu + ((x >> 16) & 1u);
    return (u16)(r >> 16);
}
// pack 8 fp32 -> 8 bf16 (one uint4)
__device__ __forceinline__ uint4 cvt8(float4 a, float4 b) {
    U8 o;
    o.s[0] = f2b(a.x); o.s[1] = f2b(a.y); o.s[2] = f2b(a.z); o.s[3] = f2b(a.w);
    o.s[4] = f2b(b.x); o.s[5] = f2b(b.y); o.s[6] = f2b(b.z); o.s[7] = f2b(b.w);
    return o.u;
}

// NOTE (round-9 lesson, measured): do NOT use nontemporal stores for the
// scattered u16/f32 epilogue stores -- L2's write-coalescing merges partial
// 64B lines and halves HBM write traffic (NT doubled WRITE_SIZE 34.9->67 MB
// and cost +36 us on gemm8p<1>). Plain cached stores everywhere.

// async global->LDS, 16 B per lane; LDS dest = wave-uniform base + lane*16
__device__ __forceinline__ void gload16(const u16* g, const u16* l) {
    __builtin_amdgcn_global_load_lds(
        (const __attribute__((address_space(1))) void*)g,
        (__attribute__((address_space(3))) void*)l, 16, 0, 0);
}

// ---------------- small kernels ----------------

__global__ void __launch_bounds__(64) zero_ss(float* ss) {
    if (threadIdx.x < 2) ss[threadIdx.x] = 0.f;
}

// ---------------- fused prep kernel ----------------
// One dispatch: twvh + sumsq x2 + cvt q + cvt Wq (+ cvt v). blockIdx.x ranges:
//   [0, 1536)      twvh v2: wvh[h][c][k] = bf16(hm[h,k]*Wv[k,c]), 64k x 32c tile,
//                  k-PAIRED u32 stores (wave = 128 B contiguous, half the store
//                  instructions of the scalar-u16 version).
//   [1536, 2048)   sumsq: ss[0] += |Wv|^2 (256 blks), ss[1] += |Wq|^2 (256)
//   [2048, 3072)   cvt q  -> qb   (2,097,152 floats, exact)
//   [3072, 4608)   cvt Wq -> wqb  (3,145,728 floats, exact)
//   [4608, 6656)   cvt v  -> vb   (16,777,216 floats, 4-iter stride) [fullfat]
__global__ void __launch_bounds__(256)
prep_k(const float* __restrict__ Wv, const float* __restrict__ Wq,
       const float* __restrict__ q, const float* __restrict__ v,
       const float* __restrict__ hm, float* __restrict__ ss,
       u16* __restrict__ wvh, u16* __restrict__ qb,
       u16* __restrict__ wqb, u16* __restrict__ vb) {
    const int bid = blockIdx.x, tid = threadIdx.x;
    if (bid < 1536) {
        // ---- twvh v2: 64k x 32c tile, transpose + 8-head scale ----
        __shared__ float t[64][33];
        int bx = bid & 31, by = bid >> 5;        // 32 c-tiles x 48 k-tiles
        int cx0 = bx * 32, ky0 = by * 64;
        int tx = tid & 31, ty = tid >> 5;
#pragma unroll
        for (int j = ty; j < 64; j += 8)
            t[j][tx] = Wv[(size_t)(ky0 + j) * 1024 + cx0 + tx];
        // hv for this thread's k-pair (2tx, 2tx+1)
        int k0 = ky0 + 2 * tx;
        float hv0[8], hv1[8];
#pragma unroll
        for (int h = 0; h < 8; h++) {
            hv0[h] = hm[(size_t)h * 3072 + k0];
            hv1[h] = hm[(size_t)h * 3072 + k0 + 1];
        }
        __syncthreads();
#pragma unroll
        for (int j = ty; j < 32; j += 8) {
            float w0 = t[2 * tx][j], w1 = t[2 * tx + 1][j];
            int c = cx0 + j;
#pragma unroll
            for (int h = 0; h < 8; h++) {
                u32 val = (u32)f2b(hv0[h] * w0) | ((u32)f2b(hv1[h] * w1) << 16);
                *(u32*)(wvh + (size_t)h * 3145728 + (size_t)c * 3072 + k0) = val;
            }
        }
    } else if (bid < 2048) {
        // ---- sumsq of Wv (sub<256) / Wq ----
        int sub = bid - 1536;
        const float* W = (sub < 256) ? Wv : Wq;
        int lb = sub & 255;
        float acc = 0.f;
        const size_t stride = (size_t)256 * 256 * 8;
        for (size_t i = ((size_t)lb * 256 + tid) * 8; i < (size_t)(3072 * 1024); i += stride) {
            float4 a = *(const float4*)(W + i);
            float4 b = *(const float4*)(W + i + 4);
            acc += a.x * a.x + a.y * a.y + a.z * a.z + a.w * a.w;
            acc += b.x * b.x + b.y * b.y + b.z * b.z + b.w * b.w;
        }
#pragma unroll
        for (int o = 32; o > 0; o >>= 1) acc += __shfl_down(acc, o, 64);
        __shared__ float red[4];
        int lane = tid & 63, w6 = tid >> 6;
        if (lane == 0) red[w6] = acc;
        __syncthreads();
        if (tid == 0) atomicAdd(&ss[sub >> 8], red[0] + red[1] + red[2] + red[3]);
    } else if (bid < 3072) {
        // ---- cvt q -> qb (exact cover) ----
        size_t i = ((size_t)(bid - 2048) * 256 + tid) * 8;
        float4 a = *(const float4*)(q + i);
        float4 b = *(const float4*)(q + i + 4);
        *(uint4*)(qb + i) = cvt8(a, b);
    } else if (bid < 4608) {
        // ---- cvt Wq -> wqb (exact cover) ----
        size_t i = ((size_t)(bid - 3072) * 256 + tid) * 8;
        float4 a = *(const float4*)(Wq + i);
        float4 b = *(const float4*)(Wq + i + 4);
        *(uint4*)(wqb + i) = cvt8(a, b);
    } else {
        // ---- cvt v -> vb (grid-stride, 4 iters) ----
        const size_t stride = (size_t)2048 * 256 * 8;
        for (size_t i = ((size_t)(bid - 4608) * 256 + tid) * 8; i < (size_t)16777216; i += stride) {
            float4 a = *(const float4*)(v + i);
            float4 b = *(const float4*)(v + i + 4);
            *(uint4*)(vb + i) = cvt8(a, b);
        }
    }
}

// cb[o] = sum_k bv[k]*hm[h,k]*q_[b*128+d, k], o = b*1024 + h*128 + d.
// 256 blocks; 4 threads per output (K/4 each); shfl_xor quad-reduce; no atomics.
__global__ void __launch_bounds__(256) const_k(const u16* __restrict__ qbuf,
                                               const float* __restrict__ bv,
                                               const float* __restrict__ hm,
                                               float* __restrict__ cb) {
    int o = blockIdx.x * 64 + (threadIdx.x >> 2);   // 0..16383
    int qt = threadIdx.x & 3;                        // K quarter
    int b = o >> 10, hd = o & 1023, h = hd >> 7, d = hd & 127;
    const u16* qr = qbuf + ((size_t)b * 128 + d) * 3072 + qt * 768;
    const float* hr = hm + (size_t)h * 3072 + qt * 768;
    const float* br = bv + qt * 768;
    float acc = 0.f;
    for (int k = 0; k < 768; k += 8) {
        U8 uq; uq.u = *(const uint4*)(qr + k);
        float4 h0 = *(const float4*)(hr + k);
        float4 h1 = *(const float4*)(hr + k + 4);
        float4 b0 = *(const float4*)(br + k);
        float4 b1 = *(const float4*)(br + k + 4);
        acc += b2f(uq.s[0]) * h0.x * b0.x + b2f(uq.s[1]) * h0.y * b0.y +
               b2f(uq.s[2]) * h0.z * b0.z + b2f(uq.s[3]) * h0.w * b0.w +
               b2f(uq.s[4]) * h1.x * b1.x + b2f(uq.s[5]) * h1.y * b1.y +
               b2f(uq.s[6]) * h1.z * b1.z + b2f(uq.s[7]) * h1.w * b1.w;
    }
    acc += __shfl_xor(acc, 1, 64);
    acc += __shfl_xor(acc, 2, 64);
    if (qt == 0) cb[o] = acc;
}

// ---------------- legacy 128x128 BT-GEMM (2-phase, __syncthreads) ----------------
// kept for EPI 0 (small N, more blocks) and the fp32-A fallback of EPI 2.
// EPI 0: bijective XCD chunking -- grid (24,16), 48 blocks/XCD as 6bx x 8by;
// per-XCD operand footprint 3.5 MB < 4 MB L2.
template <int EPI, bool A_BF16>
__global__ void __launch_bounds__(256)
gemm_bt(const void* __restrict__ Ap, const u16* __restrict__ Bp, void* __restrict__ C,
        const float* __restrict__ ss, int ss_idx, const float* __restrict__ g,
        const float* __restrict__ bias, const float* __restrict__ cb,
        const float* __restrict__ hbias, int kdim, size_t abatch, size_t bbatch) {
    constexpr int BK = 32;
    __shared__ __align__(16) u16 sA[2][128 * BK];
    __shared__ __align__(16) u16 sB[2][128 * BK];

    const int tid = threadIdx.x;
    const int lane = tid & 63, wv = tid >> 6;
    const int wm = (wv & 1) * 64, wn = (wv >> 1) * 64;
    const int lr = lane & 15, quad = lane >> 4;
    const int z = blockIdx.z;

    int bxx, byy;
    if constexpr (EPI == 0) {
        int lin = blockIdx.y * 24 + blockIdx.x;     // grid (24,16)
        int xcd = lin & 7, i = lin >> 3;            // i in 0..47
        bxx = (xcd & 3) * 6 + i % 6;
        byy = (xcd >> 2) * 8 + i / 6;
    } else {
        bxx = blockIdx.x; byy = blockIdx.y;
    }
    const int arow0 = byy * 128;
    const int bcol0 = bxx * 128;

    const size_t aoff = (size_t)z * abatch;
    const size_t boff = (size_t)z * bbatch;

    const int srow = 16 * wv + (lane >> 2);
    const int qcg  = (lane & 3) ^ ((lane >> 3) & 3);
    const int lb0  = wv * 512;
    const int lb1  = lb0 + 2048;

    const u16* gB0 = Bp + boff + (size_t)(bcol0 + srow) * kdim + qcg * 8;
    const u16* gB1 = gB0 + (size_t)64 * kdim;

    const int r0 = tid >> 2, c0 = (tid & 3) * 8;
    const int w0 = r0 * 32 + (((tid & 3) ^ ((tid >> 3) & 3)) * 8);
    const int w1 = w0 + 2048;

    const u16* gA0 = nullptr; const u16* gA1 = nullptr;
    const float* fA0 = nullptr; const float* fA1 = nullptr;
    if constexpr (A_BF16) {
        gA0 = (const u16*)Ap + aoff + (size_t)(arow0 + srow) * kdim + qcg * 8;
        gA1 = gA0 + (size_t)64 * kdim;
    } else {
        fA0 = (const float*)Ap + aoff + (size_t)(arow0 + r0) * kdim + c0;
        fA1 = fA0 + (size_t)64 * kdim;
    }

    const int rsw = (quad ^ ((lr >> 1) & 3)) * 8;

    if constexpr (A_BF16) {
        gload16(gA0, sA[0] + lb0);
        gload16(gA1, sA[0] + lb1);
        gA0 += BK; gA1 += BK;
    } else {
        float4 x0 = *(const float4*)fA0, x1 = *(const float4*)(fA0 + 4);
        float4 y0 = *(const float4*)fA1, y1 = *(const float4*)(fA1 + 4);
        *(uint4*)(sA[0] + w0) = cvt8(x0, x1);
        *(uint4*)(sA[0] + w1) = cvt8(y0, y1);
        fA0 += BK; fA1 += BK;
    }
    gload16(gB0, sB[0] + lb0);
    gload16(gB1, sB[0] + lb1);
    gB0 += BK; gB1 += BK;

    f32x4 acc[4][4];
#pragma unroll
    for (int im = 0; im < 4; im++)
#pragma unroll
        for (int in = 0; in < 4; in++) acc[im][in] = (f32x4){0.f, 0.f, 0.f, 0.f};

    __syncthreads();

    int p = 0;
    for (int kt = 0; kt < kdim; kt += BK) {
        const bool more = (kt + BK < kdim);

        float4 ax0, ax1, ay0, ay1;
        if (more) {
            if constexpr (A_BF16) {
                gload16(gA0, sA[p ^ 1] + lb0);
                gload16(gA1, sA[p ^ 1] + lb1);
                gA0 += BK; gA1 += BK;
            } else {
                ax0 = *(const float4*)fA0; ax1 = *(const float4*)(fA0 + 4);
                ay0 = *(const float4*)fA1; ay1 = *(const float4*)(fA1 + 4);
                fA0 += BK; fA1 += BK;
            }
            gload16(gB0, sB[p ^ 1] + lb0);
            gload16(gB1, sB[p ^ 1] + lb1);
            gB0 += BK; gB1 += BK;
        }

        const u16* sAp = sA[p];
        const u16* sBp = sB[p];
        bf16x8 af[4], bfr[4];
#pragma unroll
        for (int im = 0; im < 4; im++)
            af[im] = *(const bf16x8*)(sAp + (wm + im * 16 + lr) * 32 + rsw);
#pragma unroll
        for (int in = 0; in < 4; in++)
            bfr[in] = *(const bf16x8*)(sBp + (wn + in * 16 + lr) * 32 + rsw);
#pragma unroll
        for (int im = 0; im < 4; im++)
#pragma unroll
            for (int in = 0; in < 4; in++)
                acc[im][in] = __builtin_amdgcn_mfma_f32_16x16x32_bf16(af[im], bfr[in], acc[im][in], 0, 0, 0);

        if (more) {
            if constexpr (!A_BF16) {
                u16* dA = sA[p ^ 1];
                *(uint4*)(dA + w0) = cvt8(ax0, ax1);
                *(uint4*)(dA + w1) = cvt8(ay0, ay1);
            }
        }
        __syncthreads();
        p ^= 1;
    }

    float scale = 1.f;
    if constexpr (EPI == 0 || EPI == 2) scale = g[0] / sqrtf(ss[ss_idx]);

#pragma unroll
    for (int im = 0; im < 4; im++) {
#pragma unroll
        for (int in = 0; in < 4; in++) {
#pragma unroll
            for (int reg = 0; reg < 4; reg++) {
                int gr = arow0 + wm + im * 16 + quad * 4 + reg;
                int gc = bcol0 + wn + in * 16 + lr;
                float val = acc[im][in][reg];
                if constexpr (EPI == 0) {
                    ((u16*)C)[(size_t)gr * 3072 + gc] = f2b(val * scale + bias[gc]);
                } else if constexpr (EPI == 1) {
                    size_t idx = (((size_t)(gr >> 7) * 8 + (gc >> 10)) * 128 + (gr & 127)) * 1024
                               + (gc & 1023);
                    ((u16*)C)[idx] = f2b(val);
                } else {
                    int h = gc >> 7, d = gc & 127;
                    float o = val * scale + cb[(size_t)z * 1024 + gc] + hbias[h];
                    ((float*)C)[(((size_t)z * 8 + h) * 1024 + gr) * 128 + d] = o;
                }
            }
        }
    }
}

// ---------------- 256x256 BT-GEMM, single-barrier-per-tile free-running pipeline --------
// (hot loop unchanged from round 6 -- proven 85 us / MfmaUtil 52%)
// EPI 2: z-locality XCD chunking (XCD k owns z in {k, k+8}).
// Epilogue stores are PLAIN cached stores (round-9 NT regression: +36 us).
template <int EPI>
__global__ void __launch_bounds__(512, 2)
gemm8p(const u16* __restrict__ Ap, const u16* __restrict__ Bp, void* __restrict__ C,
       const float* __restrict__ ss, const float* __restrict__ g,
       const float* __restrict__ cb, const float* __restrict__ hbias,
       int kdim, size_t abatch, size_t bbatch) {
    __shared__ __align__(16) u16 sAb[2][256 * 64];
    __shared__ __align__(16) u16 sBb[2][256 * 64];

    const int tid = threadIdx.x;
    const int lane = tid & 63, wv = tid >> 6;
    const int wm = (wv & 1) * 128;            // M warp offset (2 warps)
    const int wn = (wv >> 1) * 64;            // N warp offset (4 warps)
    const int lr = lane & 15, quad = lane >> 4;

    int bx, by, z;
    if constexpr (EPI == 1) {
        // T1 chunked XCD swizzle: XCD k owns bx in [4k,4k+4), by 0..7
        int orig = blockIdx.y * 32 + blockIdx.x;       // gridDim = (32,8)
        int xcd = orig & 7, idx = orig >> 3;
        bx = (xcd << 2) | (idx & 3);
        by = idx >> 2;
        z = 0;
    } else {
        // z-locality: grid (4,4,16) -> XCD k runs z=k then z=k+8
        int lin = (blockIdx.z * 4 + blockIdx.y) * 4 + blockIdx.x;  // 0..255
        int xcd = lin & 7, i = lin >> 3;                           // i in 0..31
        z = xcd + 8 * (i >> 4);
        int sub = i & 15;
        bx = sub & 3; by = sub >> 2;
    }
    const int arow0 = by * 256, bcol0 = bx * 256;

    const size_t aoff = (size_t)z * abatch, boff = (size_t)z * bbatch;

    // staging lane map: call = 64 rows x 64 cols (8KB); thread covers row tid>>3,
    // 16B-group tid&7, fetching pre-swizzled global group (tid&7) ^ (row&7)
    const int sg = (tid & 7) ^ ((tid >> 3) & 7);
    const u16* gA = Ap + aoff + (size_t)(arow0 + (tid >> 3)) * kdim + sg * 8;
    const u16* gB = Bp + boff + (size_t)(bcol0 + (tid >> 3)) * kdim + sg * 8;
    const size_t ldk64 = (size_t)64 * kdim;    // 64-row call stride (elements)
    const int ldst = wv * 512;                 // wave's u16 offset within a call

    // frag read bases (u16): row*64 + slot*8, slot = quad ^ (row&7); ks=1 -> ^32
    const int slot = (quad ^ (lane & 7)) * 8;
    const int rbA = (wm + lr) * 64 + slot;
    const int rbB = (wn + lr) * 64 + slot;

    f32x4 acc[8][4];
#pragma unroll
    for (int im = 0; im < 8; im++)
#pragma unroll
        for (int in = 0; in < 4; in++) acc[im][in] = (f32x4){0.f, 0.f, 0.f, 0.f};

    // ---- prologue: stage K-tile 0 into buf 0, full drain ----
    gload16(gB + 0 * ldk64, sBb[0] + 0 * 4096 + ldst);
    gload16(gB + 1 * ldk64, sBb[0] + 1 * 4096 + ldst);
    gload16(gB + 2 * ldk64, sBb[0] + 2 * 4096 + ldst);
    gload16(gB + 3 * ldk64, sBb[0] + 3 * 4096 + ldst);
    gload16(gA + 0 * ldk64, sAb[0] + 0 * 4096 + ldst);
    gload16(gA + 1 * ldk64, sAb[0] + 1 * 4096 + ldst);
    gload16(gA + 2 * ldk64, sAb[0] + 2 * 4096 + ldst);
    gload16(gA + 3 * ldk64, sAb[0] + 3 * 4096 + ldst);
    gA += 64; gB += 64;                        // -> K-tile 1 columns
    asm volatile("s_waitcnt vmcnt(0)" ::: "memory");
    __builtin_amdgcn_s_barrier();

    const u16* sAd = sAb[0];
    const u16* sBd = sBb[0];
    u16* dA = (u16*)sAb[1];
    u16* dB = (u16*)sBb[1];

    bf16x8 af[4], bfr[4], af1[4], af2[4], bf2[4], af3[4];
    // Q0 frags for tile 0
#pragma unroll
    for (int n = 0; n < 4; n++) bfr[n] = *(const bf16x8*)(sBd + rbB + n * 1024);
#pragma unroll
    for (int j = 0; j < 4; j++) af[j] = *(const bf16x8*)(sAd + rbA + j * 1024);

    const int NT = kdim >> 6;
    for (int t = 0; t < NT; ++t) {
        const bool stg = (t + 1 < NT);

        // stage next tile -> D (burst, max slack before the tile-end vmcnt(0))
        if (stg) {
            gload16(gB + 0 * ldk64, dB + 0 * 4096 + ldst);
            gload16(gB + 1 * ldk64, dB + 1 * 4096 + ldst);
            gload16(gB + 2 * ldk64, dB + 2 * 4096 + ldst);
            gload16(gB + 3 * ldk64, dB + 3 * 4096 + ldst);
            gload16(gA + 0 * ldk64, dA + 0 * 4096 + ldst);
            gload16(gA + 1 * ldk64, dA + 1 * 4096 + ldst);
            gload16(gA + 2 * ldk64, dA + 2 * 4096 + ldst);
            gload16(gA + 3 * ldk64, dA + 3 * 4096 + ldst);
        }

        // ---- read Q1, MFMA Q0 ----
#pragma unroll
        for (int j = 0; j < 4; j++) af1[j] = *(const bf16x8*)(sAd + rbA + (4 + j) * 1024);
        __builtin_amdgcn_s_setprio(1);
#pragma unroll
        for (int j = 0; j < 4; j++)
#pragma unroll
            for (int n = 0; n < 4; n++)
                acc[j][n] = __builtin_amdgcn_mfma_f32_16x16x32_bf16(af[j], bfr[n], acc[j][n], 0, 0, 0);
        __builtin_amdgcn_s_setprio(0);

        // ---- read Q2, MFMA Q1 ----
#pragma unroll
        for (int n = 0; n < 4; n++) bf2[n] = *(const bf16x8*)(sBd + (rbB ^ 32) + n * 1024);
#pragma unroll
        for (int j = 0; j < 4; j++) af2[j] = *(const bf16x8*)(sAd + (rbA ^ 32) + j * 1024);
        __builtin_amdgcn_s_setprio(1);
#pragma unroll
        for (int j = 0; j < 4; j++)
#pragma unroll
            for (int n = 0; n < 4; n++)
                acc[4 + j][n] = __builtin_amdgcn_mfma_f32_16x16x32_bf16(af1[j], bfr[n], acc[4 + j][n], 0, 0, 0);
        __builtin_amdgcn_s_setprio(0);

        // ---- read Q3, MFMA Q2 ----
#pragma unroll
        for (int j = 0; j < 4; j++) af3[j] = *(const bf16x8*)(sAd + (rbA ^ 32) + (4 + j) * 1024);
        __builtin_amdgcn_s_setprio(1);
#pragma unroll
        for (int j = 0; j < 4; j++)
#pragma unroll
            for (int n = 0; n < 4; n++)
                acc[j][n] = __builtin_amdgcn_mfma_f32_16x16x32_bf16(af2[j], bf2[n], acc[j][n], 0, 0, 0);
        __builtin_amdgcn_s_setprio(0);

        // ---- tile-end sync (the only barrier) ----
        asm volatile("s_waitcnt vmcnt(0)" ::: "memory");   // D fully staged
        asm volatile("s_waitcnt lgkmcnt(0)" ::: "memory"); // my reads of R done
        __builtin_amdgcn_s_barrier();

        // ---- read next tile's Q0 from D, MFMA Q3 ----
        if (stg) {
#pragma unroll
            for (int n = 0; n < 4; n++) bfr[n] = *(const bf16x8*)(dB + rbB + n * 1024);
#pragma unroll
            for (int j = 0; j < 4; j++) af[j] = *(const bf16x8*)(dA + rbA + j * 1024);
        }
        __builtin_amdgcn_s_setprio(1);
#pragma unroll
        for (int j = 0; j < 4; j++)
#pragma unroll
            for (int n = 0; n < 4; n++)
                acc[4 + j][n] = __builtin_amdgcn_mfma_f32_16x16x32_bf16(af3[j], bf2[n], acc[4 + j][n], 0, 0, 0);
        __builtin_amdgcn_s_setprio(0);

        // swap dbufs, advance K
        const u16* tp = sAd; sAd = dA; dA = (u16*)tp;
        tp = sBd; sBd = dB; dB = (u16*)tp;
        gA += 64; gB += 64;
    }

    // ---- epilogue ----
    float scale = 1.f;
    if constexpr (EPI == 2) scale = g[0] / sqrtf(ss[0]);

#pragma unroll
    for (int im = 0; im < 8; im++) {
#pragma unroll
        for (int in = 0; in < 4; in++) {
#pragma unroll
            for (int reg = 0; reg < 4; reg++) {
                int gr = arow0 + wm + im * 16 + quad * 4 + reg;  // row (M)
                int gc = bcol0 + wn + in * 16 + lr;              // col (N)
                float val = acc[im][in][reg];
                if constexpr (EPI == 1) {
                    // gr = b*128+d (M=2048), gc = h*1024+c (N=8192) -> tbuf[b][h][d][c]
                    size_t idx = (((size_t)(gr >> 7) * 8 + (gc >> 10)) * 128 + (gr & 127)) * 1024
                               + (gc & 1023);
                    ((u16*)C)[idx] = f2b(val);
                } else {
                    int h = gc >> 7, d = gc & 127;
                    float o = val * scale + cb[(size_t)z * 1024 + gc] + hbias[h];
                    ((float*)C)[(((size_t)z * 8 + h) * 1024 + gr) * 128 + d] = o;
                }
            }
        }
    }
}

// ---------------- launch ----------------

extern "C" void kernel_launch(void* const* d_in, const int* in_sizes, int n_in,
                              void* d_out, int out_size, void* d_ws, size_t ws_size,
                              hipStream_t stream) {
    (void)in_sizes; (void)n_in; (void)out_size;
    const float* v  = (const float*)d_in[0];   // (16,1024,1024) fp32
    const float* q  = (const float*)d_in[1];   // (16,128,1024)  fp32
    const float* Wv = (const float*)d_in[2];   // (3072,1024)    fp32
    const float* gv = (const float*)d_in[3];
    const float* bv = (const float*)d_in[4];   // (3072)
    const float* Wq = (const float*)d_in[5];   // (3072,1024)
    const float* gq = (const float*)d_in[6];
    const float* bq = (const float*)d_in[7];   // (3072)
    const float* hm = (const float*)d_in[8];   // (8,3072)
    const float* hb = (const float*)d_in[9];   // (8)
    float* out = (float*)d_out;                // fp32 output (16,8,1024,128) = 67 MB

    // workspace layout (floor 46.2 MB; +33.5 MB vb if available)
    char* ws = (char*)d_ws;
    float* ss   = (float*)ws;                          // 256 B
    float* cb   = (float*)(ws + 256);                  // 64 KB
    u16*   qbuf = (u16*)(ws + 256 + 65536);            // 2048*3072 bf16 = 12 MB
    u16*   tbuf = (u16*)(ws + 256 + 65536 + 12582912); // 16*8*128*1024 bf16 = 33.5 MB
    u16*   vb   = (u16*)(ws + 256 + 65536 + 12582912 + 33554432);  // optional 33.5 MB
    const size_t need_vb = 256 + 65536 + 12582912 + 33554432 + 33554432;  // ~80.2 MB
    const bool fullfat = (ws_size >= need_vb);

    // scratch in d_out (67.1 MB), all dead before the final gemm writes out:
    //   wvh 8*1024*3072 bf16 = 50.33 MB | qb 2048*1024 bf16 = 4.19 MB | wqb 3072*1024 bf16 = 6.29 MB
    u16* wvh = (u16*)d_out;
    u16* qb  = (u16*)((char*)d_out + 50331648);
    u16* wqb = (u16*)((char*)d_out + 54525952);   // ends at 60.8 MB < 67.1 MB

    zero_ss<<<1, 64, 0, stream>>>(ss);

    // fused prep: twvh + sumsq + cvt q + cvt Wq (+ cvt v when fullfat)
    prep_k<<<fullfat ? 6656 : 4608, 256, 0, stream>>>(
        Wv, Wq, q, v, hm, ss, wvh, qb, wqb, vb);

    // q_ = q * wn(Wq)^T + bq   (2048 x 3072)
    gemm_bt<0, true><<<dim3(24, 16, 1), 256, 0, stream>>>(
        qb, wqb, qbuf, ss, 1, gq, bq, nullptr, nullptr, 1024, 0, 0);

    // cb[b,hd] = sum_k bv*hm*q_
    const_k<<<256, 256, 0, stream>>>(qbuf, bv, hm, cb);

    // T[b,h,d,c] = sum_k q_[b,d,k] * wvh[h,c,k]  -- ONE GEMM: M=2048, N=8192, K=3072
    gemm8p<1><<<dim3(32, 8, 1), 512, 0, stream>>>(
        qbuf, wvh, tbuf, nullptr, nullptr, nullptr, nullptr, 3072, 0, 0);

    // logits[b,h,n,d] = scale_v * sum_c v[b,n,c]*T[b,hd,c] + cb[b,hd] + hbias[h]
    if (fullfat) {
        gemm8p<2><<<dim3(4, 4, 16), 512, 0, stream>>>(
            vb, tbuf, out, ss, gv, cb, hb, 1024, 1048576, 1048576);
    } else {
        gemm_bt<2, false><<<dim3(8, 8, 16), 256, 0, stream>>>(
            v, tbuf, out, ss, 0, gv, nullptr, cb, hb, 1024, 1048576, 1048576);
    }
}

// Round 11
// 360.004 us; speedup vs baseline: 1.1538x; 1.0113x over previous
//
#include <hip/hip_runtime.h>
#include <hip/hip_bf16.h>
#include <math.h>

typedef unsigned short u16;
typedef unsigned int u32;

typedef __bf16 bf16x8 __attribute__((ext_vector_type(8)));
typedef float f32x4 __attribute__((ext_vector_type(4)));

union U8 { uint4 u; u16 s[8]; };

__device__ __forceinline__ float b2f(u16 x) {
    u32 y = ((u32)x) << 16;
    return __builtin_bit_cast(float, y);
}
__device__ __forceinline__ u16 f2b(float f) {
    u32 x = __builtin_bit_cast(u32, f);
    u32 r = x + 0x7fffu + ((x >> 16) & 1u);
    return (u16)(r >> 16);
}
// pack 8 fp32 -> 8 bf16 (one uint4)
__device__ __forceinline__ uint4 cvt8(float4 a, float4 b) {
    U8 o;
    o.s[0] = f2b(a.x); o.s[1] = f2b(a.y); o.s[2] = f2b(a.z); o.s[3] = f2b(a.w);
    o.s[4] = f2b(b.x); o.s[5] = f2b(b.y); o.s[6] = f2b(b.z); o.s[7] = f2b(b.w);
    return o.u;
}

// NOTE (round-9 lesson, measured): do NOT use nontemporal stores for the
// scattered u16/f32 epilogue stores -- L2's write-coalescing merges partial
// 64B lines and halves HBM write traffic (NT doubled WRITE_SIZE 34.9->67 MB
// and cost +36 us on gemm8p<1>). Plain cached stores everywhere.

// async global->LDS, 16 B per lane; LDS dest = wave-uniform base + lane*16
__device__ __forceinline__ void gload16(const u16* g, const u16* l) {
    __builtin_amdgcn_global_load_lds(
        (const __attribute__((address_space(1))) void*)g,
        (__attribute__((address_space(3))) void*)l, 16, 0, 0);
}

// ---------------- small kernels ----------------

__global__ void __launch_bounds__(64) zero_ss(float* ss) {
    if (threadIdx.x < 2) ss[threadIdx.x] = 0.f;
}

// ---------------- fused prep kernel ----------------
// One dispatch: twvh + sumsq x2 + cvt q + cvt Wq (+ cvt v). blockIdx.x ranges:
//   [0, 1536)      twvh v2: wvh[h][c][k] = bf16(hm[h,k]*Wv[k,c]), 64k x 32c tile,
//                  k-PAIRED u32 stores (wave = 128 B contiguous).
//   [1536, 2048)   sumsq: ss[0] += |Wv|^2 (256 blks), ss[1] += |Wq|^2 (256)
//   [2048, 3072)   cvt q  -> qb   (2,097,152 floats, exact)
//   [3072, 4608)   cvt Wq -> wqb  (3,145,728 floats, exact)
//   [4608, 6656)   cvt v  -> vb   (16,777,216 floats, 4-iter stride) [fullfat]
__global__ void __launch_bounds__(256)
prep_k(const float* __restrict__ Wv, const float* __restrict__ Wq,
       const float* __restrict__ q, const float* __restrict__ v,
       const float* __restrict__ hm, float* __restrict__ ss,
       u16* __restrict__ wvh, u16* __restrict__ qb,
       u16* __restrict__ wqb, u16* __restrict__ vb) {
    const int bid = blockIdx.x, tid = threadIdx.x;
    if (bid < 1536) {
        // ---- twvh v2: 64k x 32c tile, transpose + 8-head scale ----
        __shared__ float t[64][33];
        int bx = bid & 31, by = bid >> 5;        // 32 c-tiles x 48 k-tiles
        int cx0 = bx * 32, ky0 = by * 64;
        int tx = tid & 31, ty = tid >> 5;
#pragma unroll
        for (int j = ty; j < 64; j += 8)
            t[j][tx] = Wv[(size_t)(ky0 + j) * 1024 + cx0 + tx];
        // hv for this thread's k-pair (2tx, 2tx+1)
        int k0 = ky0 + 2 * tx;
        float hv0[8], hv1[8];
#pragma unroll
        for (int h = 0; h < 8; h++) {
            hv0[h] = hm[(size_t)h * 3072 + k0];
            hv1[h] = hm[(size_t)h * 3072 + k0 + 1];
        }
        __syncthreads();
#pragma unroll
        for (int j = ty; j < 32; j += 8) {
            float w0 = t[2 * tx][j], w1 = t[2 * tx + 1][j];
            int c = cx0 + j;
#pragma unroll
            for (int h = 0; h < 8; h++) {
                u32 val = (u32)f2b(hv0[h] * w0) | ((u32)f2b(hv1[h] * w1) << 16);
                *(u32*)(wvh + (size_t)h * 3145728 + (size_t)c * 3072 + k0) = val;
            }
        }
    } else if (bid < 2048) {
        // ---- sumsq of Wv (sub<256) / Wq ----
        int sub = bid - 1536;
        const float* W = (sub < 256) ? Wv : Wq;
        int lb = sub & 255;
        float acc = 0.f;
        const size_t stride = (size_t)256 * 256 * 8;
        for (size_t i = ((size_t)lb * 256 + tid) * 8; i < (size_t)(3072 * 1024); i += stride) {
            float4 a = *(const float4*)(W + i);
            float4 b = *(const float4*)(W + i + 4);
            acc += a.x * a.x + a.y * a.y + a.z * a.z + a.w * a.w;
            acc += b.x * b.x + b.y * b.y + b.z * b.z + b.w * b.w;
        }
#pragma unroll
        for (int o = 32; o > 0; o >>= 1) acc += __shfl_down(acc, o, 64);
        __shared__ float red[4];
        int lane = tid & 63, w6 = tid >> 6;
        if (lane == 0) red[w6] = acc;
        __syncthreads();
        if (tid == 0) atomicAdd(&ss[sub >> 8], red[0] + red[1] + red[2] + red[3]);
    } else if (bid < 3072) {
        // ---- cvt q -> qb (exact cover) ----
        size_t i = ((size_t)(bid - 2048) * 256 + tid) * 8;
        float4 a = *(const float4*)(q + i);
        float4 b = *(const float4*)(q + i + 4);
        *(uint4*)(qb + i) = cvt8(a, b);
    } else if (bid < 4608) {
        // ---- cvt Wq -> wqb (exact cover) ----
        size_t i = ((size_t)(bid - 3072) * 256 + tid) * 8;
        float4 a = *(const float4*)(Wq + i);
        float4 b = *(const float4*)(Wq + i + 4);
        *(uint4*)(wqb + i) = cvt8(a, b);
    } else {
        // ---- cvt v -> vb (grid-stride, 4 iters) ----
        const size_t stride = (size_t)2048 * 256 * 8;
        for (size_t i = ((size_t)(bid - 4608) * 256 + tid) * 8; i < (size_t)16777216; i += stride) {
            float4 a = *(const float4*)(v + i);
            float4 b = *(const float4*)(v + i + 4);
            *(uint4*)(vb + i) = cvt8(a, b);
        }
    }
}

// cb[o] = sum_k bv[k]*hm[h,k]*q_[b*128+d, k], o = b*1024 + h*128 + d.
// 256 blocks; 4 threads per output (K/4 each); shfl_xor quad-reduce; no atomics.
__global__ void __launch_bounds__(256) const_k(const u16* __restrict__ qbuf,
                                               const float* __restrict__ bv,
                                               const float* __restrict__ hm,
                                               float* __restrict__ cb) {
    int o = blockIdx.x * 64 + (threadIdx.x >> 2);   // 0..16383
    int qt = threadIdx.x & 3;                        // K quarter
    int b = o >> 10, hd = o & 1023, h = hd >> 7, d = hd & 127;
    const u16* qr = qbuf + ((size_t)b * 128 + d) * 3072 + qt * 768;
    const float* hr = hm + (size_t)h * 3072 + qt * 768;
    const float* br = bv + qt * 768;
    float acc = 0.f;
    for (int k = 0; k < 768; k += 8) {
        U8 uq; uq.u = *(const uint4*)(qr + k);
        float4 h0 = *(const float4*)(hr + k);
        float4 h1 = *(const float4*)(hr + k + 4);
        float4 b0 = *(const float4*)(br + k);
        float4 b1 = *(const float4*)(br + k + 4);
        acc += b2f(uq.s[0]) * h0.x * b0.x + b2f(uq.s[1]) * h0.y * b0.y +
               b2f(uq.s[2]) * h0.z * b0.z + b2f(uq.s[3]) * h0.w * b0.w +
               b2f(uq.s[4]) * h1.x * b1.x + b2f(uq.s[5]) * h1.y * b1.y +
               b2f(uq.s[6]) * h1.z * b1.z + b2f(uq.s[7]) * h1.w * b1.w;
    }
    acc += __shfl_xor(acc, 1, 64);
    acc += __shfl_xor(acc, 2, 64);
    if (qt == 0) cb[o] = acc;
}

// ---------------- legacy 128x128 BT-GEMM (2-phase, __syncthreads) ----------------
// kept for EPI 0 (small N, more blocks) and the fp32-A fallback of EPI 2.
// EPI 0: bijective XCD chunking -- grid (24,16), 48 blocks/XCD as 6bx x 8by;
// per-XCD operand footprint 3.5 MB < 4 MB L2.
template <int EPI, bool A_BF16>
__global__ void __launch_bounds__(256)
gemm_bt(const void* __restrict__ Ap, const u16* __restrict__ Bp, void* __restrict__ C,
        const float* __restrict__ ss, int ss_idx, const float* __restrict__ g,
        const float* __restrict__ bias, const float* __restrict__ cb,
        const float* __restrict__ hbias, int kdim, size_t abatch, size_t bbatch) {
    constexpr int BK = 32;
    __shared__ __align__(16) u16 sA[2][128 * BK];
    __shared__ __align__(16) u16 sB[2][128 * BK];

    const int tid = threadIdx.x;
    const int lane = tid & 63, wv = tid >> 6;
    const int wm = (wv & 1) * 64, wn = (wv >> 1) * 64;
    const int lr = lane & 15, quad = lane >> 4;
    const int z = blockIdx.z;

    int bxx, byy;
    if constexpr (EPI == 0) {
        int lin = blockIdx.y * 24 + blockIdx.x;     // grid (24,16)
        int xcd = lin & 7, i = lin >> 3;            // i in 0..47
        bxx = (xcd & 3) * 6 + i % 6;
        byy = (xcd >> 2) * 8 + i / 6;
    } else {
        bxx = blockIdx.x; byy = blockIdx.y;
    }
    const int arow0 = byy * 128;
    const int bcol0 = bxx * 128;

    const size_t aoff = (size_t)z * abatch;
    const size_t boff = (size_t)z * bbatch;

    const int srow = 16 * wv + (lane >> 2);
    const int qcg  = (lane & 3) ^ ((lane >> 3) & 3);
    const int lb0  = wv * 512;
    const int lb1  = lb0 + 2048;

    const u16* gB0 = Bp + boff + (size_t)(bcol0 + srow) * kdim + qcg * 8;
    const u16* gB1 = gB0 + (size_t)64 * kdim;

    const int r0 = tid >> 2, c0 = (tid & 3) * 8;
    const int w0 = r0 * 32 + (((tid & 3) ^ ((tid >> 3) & 3)) * 8);
    const int w1 = w0 + 2048;

    const u16* gA0 = nullptr; const u16* gA1 = nullptr;
    const float* fA0 = nullptr; const float* fA1 = nullptr;
    if constexpr (A_BF16) {
        gA0 = (const u16*)Ap + aoff + (size_t)(arow0 + srow) * kdim + qcg * 8;
        gA1 = gA0 + (size_t)64 * kdim;
    } else {
        fA0 = (const float*)Ap + aoff + (size_t)(arow0 + r0) * kdim + c0;
        fA1 = fA0 + (size_t)64 * kdim;
    }

    const int rsw = (quad ^ ((lr >> 1) & 3)) * 8;

    if constexpr (A_BF16) {
        gload16(gA0, sA[0] + lb0);
        gload16(gA1, sA[0] + lb1);
        gA0 += BK; gA1 += BK;
    } else {
        float4 x0 = *(const float4*)fA0, x1 = *(const float4*)(fA0 + 4);
        float4 y0 = *(const float4*)fA1, y1 = *(const float4*)(fA1 + 4);
        *(uint4*)(sA[0] + w0) = cvt8(x0, x1);
        *(uint4*)(sA[0] + w1) = cvt8(y0, y1);
        fA0 += BK; fA1 += BK;
    }
    gload16(gB0, sB[0] + lb0);
    gload16(gB1, sB[0] + lb1);
    gB0 += BK; gB1 += BK;

    f32x4 acc[4][4];
#pragma unroll
    for (int im = 0; im < 4; im++)
#pragma unroll
        for (int in = 0; in < 4; in++) acc[im][in] = (f32x4){0.f, 0.f, 0.f, 0.f};

    __syncthreads();

    int p = 0;
    for (int kt = 0; kt < kdim; kt += BK) {
        const bool more = (kt + BK < kdim);

        float4 ax0, ax1, ay0, ay1;
        if (more) {
            if constexpr (A_BF16) {
                gload16(gA0, sA[p ^ 1] + lb0);
                gload16(gA1, sA[p ^ 1] + lb1);
                gA0 += BK; gA1 += BK;
            } else {
                ax0 = *(const float4*)fA0; ax1 = *(const float4*)(fA0 + 4);
                ay0 = *(const float4*)fA1; ay1 = *(const float4*)(fA1 + 4);
                fA0 += BK; fA1 += BK;
            }
            gload16(gB0, sB[p ^ 1] + lb0);
            gload16(gB1, sB[p ^ 1] + lb1);
            gB0 += BK; gB1 += BK;
        }

        const u16* sAp = sA[p];
        const u16* sBp = sB[p];
        bf16x8 af[4], bfr[4];
#pragma unroll
        for (int im = 0; im < 4; im++)
            af[im] = *(const bf16x8*)(sAp + (wm + im * 16 + lr) * 32 + rsw);
#pragma unroll
        for (int in = 0; in < 4; in++)
            bfr[in] = *(const bf16x8*)(sBp + (wn + in * 16 + lr) * 32 + rsw);
#pragma unroll
        for (int im = 0; im < 4; im++)
#pragma unroll
            for (int in = 0; in < 4; in++)
                acc[im][in] = __builtin_amdgcn_mfma_f32_16x16x32_bf16(af[im], bfr[in], acc[im][in], 0, 0, 0);

        if (more) {
            if constexpr (!A_BF16) {
                u16* dA = sA[p ^ 1];
                *(uint4*)(dA + w0) = cvt8(ax0, ax1);
                *(uint4*)(dA + w1) = cvt8(ay0, ay1);
            }
        }
        __syncthreads();
        p ^= 1;
    }

    float scale = 1.f;
    if constexpr (EPI == 0 || EPI == 2) scale = g[0] / sqrtf(ss[ss_idx]);

#pragma unroll
    for (int im = 0; im < 4; im++) {
#pragma unroll
        for (int in = 0; in < 4; in++) {
#pragma unroll
            for (int reg = 0; reg < 4; reg++) {
                int gr = arow0 + wm + im * 16 + quad * 4 + reg;
                int gc = bcol0 + wn + in * 16 + lr;
                float val = acc[im][in][reg];
                if constexpr (EPI == 0) {
                    ((u16*)C)[(size_t)gr * 3072 + gc] = f2b(val * scale + bias[gc]);
                } else if constexpr (EPI == 1) {
                    size_t idx = (((size_t)(gr >> 7) * 8 + (gc >> 10)) * 128 + (gr & 127)) * 1024
                               + (gc & 1023);
                    ((u16*)C)[idx] = f2b(val);
                } else {
                    int h = gc >> 7, d = gc & 127;
                    float o = val * scale + cb[(size_t)z * 1024 + gc] + hbias[h];
                    ((float*)C)[(((size_t)z * 8 + h) * 1024 + gr) * 128 + d] = o;
                }
            }
        }
    }
}

// ---------------- 256x256 BT-GEMM, single-barrier-per-tile free-running pipeline --------
// ROUND-11: tail-staging. Stages for tile t+2 are issued in tile t's TAIL
// (right after the lgkm-drain + barrier, when read-buffer P[t&1] is dead until
// t+2). vs round-10's top-of-body staging this gains the tail's duration of
// vmcnt slack and moves the 8-gload burst off the body's critical path.
// Hazard ledger:
//   - writes to P[t&1] issue only after barrier(t), which follows lgkmcnt(0)
//     on ALL waves' reads of P[t&1]  -> no read-overwrite race.
//   - stage(t+2) is drained by the vmcnt(0) at end of body(t+1); at that point
//     it is the only outstanding VMEM (stage(t+3) issues after that barrier).
//     Slack = tail(t) + body(t+1).
//   - prologue stages tiles 0 AND 1; vmcnt(8) drains only tile 0's 8 loads
//     (FIFO per wave), tile 1's fly under body(0), drained at its end.
//   - last tiles: t+2 >= NT -> no stage; vmcnt(0) trivially satisfied.
// EPI 2: z-locality XCD chunking (XCD k owns z in {k, k+8}).
// Epilogue stores are PLAIN cached stores (round-9 NT regression: +36 us).
template <int EPI>
__global__ void __launch_bounds__(512, 2)
gemm8p(const u16* __restrict__ Ap, const u16* __restrict__ Bp, void* __restrict__ C,
       const float* __restrict__ ss, const float* __restrict__ g,
       const float* __restrict__ cb, const float* __restrict__ hbias,
       int kdim, size_t abatch, size_t bbatch) {
    __shared__ __align__(16) u16 sAb[2][256 * 64];
    __shared__ __align__(16) u16 sBb[2][256 * 64];

    const int tid = threadIdx.x;
    const int lane = tid & 63, wv = tid >> 6;
    const int wm = (wv & 1) * 128;            // M warp offset (2 warps)
    const int wn = (wv >> 1) * 64;            // N warp offset (4 warps)
    const int lr = lane & 15, quad = lane >> 4;

    int bx, by, z;
    if constexpr (EPI == 1) {
        // T1 chunked XCD swizzle: XCD k owns bx in [4k,4k+4), by 0..7
        int orig = blockIdx.y * 32 + blockIdx.x;       // gridDim = (32,8)
        int xcd = orig & 7, idx = orig >> 3;
        bx = (xcd << 2) | (idx & 3);
        by = idx >> 2;
        z = 0;
    } else {
        // z-locality: grid (4,4,16) -> XCD k runs z=k then z=k+8
        int lin = (blockIdx.z * 4 + blockIdx.y) * 4 + blockIdx.x;  // 0..255
        int xcd = lin & 7, i = lin >> 3;                           // i in 0..31
        z = xcd + 8 * (i >> 4);
        int sub = i & 15;
        bx = sub & 3; by = sub >> 2;
    }
    const int arow0 = by * 256, bcol0 = bx * 256;

    const size_t aoff = (size_t)z * abatch, boff = (size_t)z * bbatch;

    // staging lane map: call = 64 rows x 64 cols (8KB); thread covers row tid>>3,
    // 16B-group tid&7, fetching pre-swizzled global group (tid&7) ^ (row&7)
    const int sg = (tid & 7) ^ ((tid >> 3) & 7);
    const u16* gA = Ap + aoff + (size_t)(arow0 + (tid >> 3)) * kdim + sg * 8;
    const u16* gB = Bp + boff + (size_t)(bcol0 + (tid >> 3)) * kdim + sg * 8;
    const size_t ldk64 = (size_t)64 * kdim;    // 64-row call stride (elements)
    const int ldst = wv * 512;                 // wave's u16 offset within a call

    // frag read bases (u16): row*64 + slot*8, slot = quad ^ (row&7); ks=1 -> ^32
    const int slot = (quad ^ (lane & 7)) * 8;
    const int rbA = (wm + lr) * 64 + slot;
    const int rbB = (wn + lr) * 64 + slot;

    f32x4 acc[8][4];
#pragma unroll
    for (int im = 0; im < 8; im++)
#pragma unroll
        for (int in = 0; in < 4; in++) acc[im][in] = (f32x4){0.f, 0.f, 0.f, 0.f};

    // ---- prologue: stage K-tile 0 -> P0 and K-tile 1 -> P1; drain only tile 0 ----
    gload16(gB + 0 * ldk64, sBb[0] + 0 * 4096 + ldst);
    gload16(gB + 1 * ldk64, sBb[0] + 1 * 4096 + ldst);
    gload16(gB + 2 * ldk64, sBb[0] + 2 * 4096 + ldst);
    gload16(gB + 3 * ldk64, sBb[0] + 3 * 4096 + ldst);
    gload16(gA + 0 * ldk64, sAb[0] + 0 * 4096 + ldst);
    gload16(gA + 1 * ldk64, sAb[0] + 1 * 4096 + ldst);
    gload16(gA + 2 * ldk64, sAb[0] + 2 * 4096 + ldst);
    gload16(gA + 3 * ldk64, sAb[0] + 3 * 4096 + ldst);
    gload16(gB + 64 + 0 * ldk64, sBb[1] + 0 * 4096 + ldst);
    gload16(gB + 64 + 1 * ldk64, sBb[1] + 1 * 4096 + ldst);
    gload16(gB + 64 + 2 * ldk64, sBb[1] + 2 * 4096 + ldst);
    gload16(gB + 64 + 3 * ldk64, sBb[1] + 3 * 4096 + ldst);
    gload16(gA + 64 + 0 * ldk64, sAb[1] + 0 * 4096 + ldst);
    gload16(gA + 64 + 1 * ldk64, sAb[1] + 1 * 4096 + ldst);
    gload16(gA + 64 + 2 * ldk64, sAb[1] + 2 * 4096 + ldst);
    gload16(gA + 64 + 3 * ldk64, sAb[1] + 3 * 4096 + ldst);
    gA += 128; gB += 128;                      // -> K-tile 2 columns
    asm volatile("s_waitcnt vmcnt(8)" ::: "memory");   // tile 0 resident; tile 1 in flight
    __builtin_amdgcn_s_barrier();

    const u16* sAd = sAb[0];
    const u16* sBd = sBb[0];
    u16* dA = (u16*)sAb[1];
    u16* dB = (u16*)sBb[1];

    bf16x8 af[4], bfr[4], af1[4], af2[4], bf2[4], af3[4];
    // Q0 frags for tile 0
#pragma unroll
    for (int n = 0; n < 4; n++) bfr[n] = *(const bf16x8*)(sBd + rbB + n * 1024);
#pragma unroll
    for (int j = 0; j < 4; j++) af[j] = *(const bf16x8*)(sAd + rbA + j * 1024);

    const int NT = kdim >> 6;
    for (int t = 0; t < NT; ++t) {
        // ---- read Q1, MFMA Q0 ----
#pragma unroll
        for (int j = 0; j < 4; j++) af1[j] = *(const bf16x8*)(sAd + rbA + (4 + j) * 1024);
        __builtin_amdgcn_s_setprio(1);
#pragma unroll
        for (int j = 0; j < 4; j++)
#pragma unroll
            for (int n = 0; n < 4; n++)
                acc[j][n] = __builtin_amdgcn_mfma_f32_16x16x32_bf16(af[j], bfr[n], acc[j][n], 0, 0, 0);
        __builtin_amdgcn_s_setprio(0);

        // ---- read Q2, MFMA Q1 ----
#pragma unroll
        for (int n = 0; n < 4; n++) bf2[n] = *(const bf16x8*)(sBd + (rbB ^ 32) + n * 1024);
#pragma unroll
        for (int j = 0; j < 4; j++) af2[j] = *(const bf16x8*)(sAd + (rbA ^ 32) + j * 1024);
        __builtin_amdgcn_s_setprio(1);
#pragma unroll
        for (int j = 0; j < 4; j++)
#pragma unroll
            for (int n = 0; n < 4; n++)
                acc[4 + j][n] = __builtin_amdgcn_mfma_f32_16x16x32_bf16(af1[j], bfr[n], acc[4 + j][n], 0, 0, 0);
        __builtin_amdgcn_s_setprio(0);

        // ---- read Q3, MFMA Q2 ----
#pragma unroll
        for (int j = 0; j < 4; j++) af3[j] = *(const bf16x8*)(sAd + (rbA ^ 32) + (4 + j) * 1024);
        __builtin_amdgcn_s_setprio(1);
#pragma unroll
        for (int j = 0; j < 4; j++)
#pragma unroll
            for (int n = 0; n < 4; n++)
                acc[j][n] = __builtin_amdgcn_mfma_f32_16x16x32_bf16(af2[j], bf2[n], acc[j][n], 0, 0, 0);
        __builtin_amdgcn_s_setprio(0);

        // ---- tile-end sync (the only barrier) ----
        asm volatile("s_waitcnt vmcnt(0)" ::: "memory");   // stage(t+1) resident
        asm volatile("s_waitcnt lgkmcnt(0)" ::: "memory"); // all my reads of P[t&1] done
        __builtin_amdgcn_s_barrier();

        // ---- tail: stage(t+2) -> P[t&1] (now dead), read next Q0 from D, MFMA Q3 ----
        if (t + 2 < NT) {
            u16* tA = (u16*)sAd;  // P[t&1]
            u16* tB = (u16*)sBd;
            gload16(gB + 0 * ldk64, tB + 0 * 4096 + ldst);
            gload16(gB + 1 * ldk64, tB + 1 * 4096 + ldst);
            gload16(gB + 2 * ldk64, tB + 2 * 4096 + ldst);
            gload16(gB + 3 * ldk64, tB + 3 * 4096 + ldst);
            gload16(gA + 0 * ldk64, tA + 0 * 4096 + ldst);
            gload16(gA + 1 * ldk64, tA + 1 * 4096 + ldst);
            gload16(gA + 2 * ldk64, tA + 2 * 4096 + ldst);
            gload16(gA + 3 * ldk64, tA + 3 * 4096 + ldst);
        }
        if (t + 1 < NT) {
#pragma unroll
            for (int n = 0; n < 4; n++) bfr[n] = *(const bf16x8*)(dB + rbB + n * 1024);
#pragma unroll
            for (int j = 0; j < 4; j++) af[j] = *(const bf16x8*)(dA + rbA + j * 1024);
        }
        __builtin_amdgcn_s_setprio(1);
#pragma unroll
        for (int j = 0; j < 4; j++)
#pragma unroll
            for (int n = 0; n < 4; n++)
                acc[4 + j][n] = __builtin_amdgcn_mfma_f32_16x16x32_bf16(af3[j], bf2[n], acc[4 + j][n], 0, 0, 0);
        __builtin_amdgcn_s_setprio(0);

        // swap dbufs, advance K
        const u16* tp = sAd; sAd = dA; dA = (u16*)tp;
        tp = sBd; sBd = dB; dB = (u16*)tp;
        gA += 64; gB += 64;
    }

    // ---- epilogue ----
    float scale = 1.f;
    if constexpr (EPI == 2) scale = g[0] / sqrtf(ss[0]);

#pragma unroll
    for (int im = 0; im < 8; im++) {
#pragma unroll
        for (int in = 0; in < 4; in++) {
#pragma unroll
            for (int reg = 0; reg < 4; reg++) {
                int gr = arow0 + wm + im * 16 + quad * 4 + reg;  // row (M)
                int gc = bcol0 + wn + in * 16 + lr;              // col (N)
                float val = acc[im][in][reg];
                if constexpr (EPI == 1) {
                    // gr = b*128+d (M=2048), gc = h*1024+c (N=8192) -> tbuf[b][h][d][c]
                    size_t idx = (((size_t)(gr >> 7) * 8 + (gc >> 10)) * 128 + (gr & 127)) * 1024
                               + (gc & 1023);
                    ((u16*)C)[idx] = f2b(val);
                } else {
                    int h = gc >> 7, d = gc & 127;
                    float o = val * scale + cb[(size_t)z * 1024 + gc] + hbias[h];
                    ((float*)C)[(((size_t)z * 8 + h) * 1024 + gr) * 128 + d] = o;
                }
            }
        }
    }
}

// ---------------- launch ----------------

extern "C" void kernel_launch(void* const* d_in, const int* in_sizes, int n_in,
                              void* d_out, int out_size, void* d_ws, size_t ws_size,
                              hipStream_t stream) {
    (void)in_sizes; (void)n_in; (void)out_size;
    const float* v  = (const float*)d_in[0];   // (16,1024,1024) fp32
    const float* q  = (const float*)d_in[1];   // (16,128,1024)  fp32
    const float* Wv = (const float*)d_in[2];   // (3072,1024)    fp32
    const float* gv = (const float*)d_in[3];
    const float* bv = (const float*)d_in[4];   // (3072)
    const float* Wq = (const float*)d_in[5];   // (3072,1024)
    const float* gq = (const float*)d_in[6];
    const float* bq = (const float*)d_in[7];   // (3072)
    const float* hm = (const float*)d_in[8];   // (8,3072)
    const float* hb = (const float*)d_in[9];   // (8)
    float* out = (float*)d_out;                // fp32 output (16,8,1024,128) = 67 MB

    // workspace layout (floor 46.2 MB; +33.5 MB vb if available)
    char* ws = (char*)d_ws;
    float* ss   = (float*)ws;                          // 256 B
    float* cb   = (float*)(ws + 256);                  // 64 KB
    u16*   qbuf = (u16*)(ws + 256 + 65536);            // 2048*3072 bf16 = 12 MB
    u16*   tbuf = (u16*)(ws + 256 + 65536 + 12582912); // 16*8*128*1024 bf16 = 33.5 MB
    u16*   vb   = (u16*)(ws + 256 + 65536 + 12582912 + 33554432);  // optional 33.5 MB
    const size_t need_vb = 256 + 65536 + 12582912 + 33554432 + 33554432;  // ~80.2 MB
    const bool fullfat = (ws_size >= need_vb);

    // scratch in d_out (67.1 MB), all dead before the final gemm writes out:
    //   wvh 8*1024*3072 bf16 = 50.33 MB | qb 2048*1024 bf16 = 4.19 MB | wqb 3072*1024 bf16 = 6.29 MB
    u16* wvh = (u16*)d_out;
    u16* qb  = (u16*)((char*)d_out + 50331648);
    u16* wqb = (u16*)((char*)d_out + 54525952);   // ends at 60.8 MB < 67.1 MB

    zero_ss<<<1, 64, 0, stream>>>(ss);

    // fused prep: twvh + sumsq + cvt q + cvt Wq (+ cvt v when fullfat)
    prep_k<<<fullfat ? 6656 : 4608, 256, 0, stream>>>(
        Wv, Wq, q, v, hm, ss, wvh, qb, wqb, vb);

    // q_ = q * wn(Wq)^T + bq   (2048 x 3072)
    gemm_bt<0, true><<<dim3(24, 16, 1), 256, 0, stream>>>(
        qb, wqb, qbuf, ss, 1, gq, bq, nullptr, nullptr, 1024, 0, 0);

    // cb[b,hd] = sum_k bv*hm*q_
    const_k<<<256, 256, 0, stream>>>(qbuf, bv, hm, cb);

    // T[b,h,d,c] = sum_k q_[b,d,k] * wvh[h,c,k]  -- ONE GEMM: M=2048, N=8192, K=3072
    gemm8p<1><<<dim3(32, 8, 1), 512, 0, stream>>>(
        qbuf, wvh, tbuf, nullptr, nullptr, nullptr, nullptr, 3072, 0, 0);

    // logits[b,h,n,d] = scale_v * sum_c v[b,n,c]*T[b,hd,c] + cb[b,hd] + hbias[h]
    if (fullfat) {
        gemm8p<2><<<dim3(4, 4, 16), 512, 0, stream>>>(
            vb, tbuf, out, ss, gv, cb, hb, 1024, 1048576, 1048576);
    } else {
        gemm_bt<2, false><<<dim3(8, 8, 16), 256, 0, stream>>>(
            v, tbuf, out, ss, 0, gv, nullptr, cb, hb, 1024, 1048576, 1048576);
    }
}

// Round 12
// 357.533 us; speedup vs baseline: 1.1618x; 1.0069x over previous
//
#include <hip/hip_runtime.h>
#include <hip/hip_bf16.h>
#include <math.h>

typedef unsigned short u16;
typedef unsigned int u32;

typedef __bf16 bf16x8 __attribute__((ext_vector_type(8)));
typedef float f32x4 __attribute__((ext_vector_type(4)));

union U8 { uint4 u; u16 s[8]; };

__device__ __forceinline__ float b2f(u16 x) {
    u32 y = ((u32)x) << 16;
    return __builtin_bit_cast(float, y);
}
__device__ __forceinline__ u16 f2b(float f) {
    u32 x = __builtin_bit_cast(u32, f);
    u32 r = x + 0x7fffu + ((x >> 16) & 1u);
    return (u16)(r >> 16);
}
// pack 8 fp32 -> 8 bf16 (one uint4)
__device__ __forceinline__ uint4 cvt8(float4 a, float4 b) {
    U8 o;
    o.s[0] = f2b(a.x); o.s[1] = f2b(a.y); o.s[2] = f2b(a.z); o.s[3] = f2b(a.w);
    o.s[4] = f2b(b.x); o.s[5] = f2b(b.y); o.s[6] = f2b(b.z); o.s[7] = f2b(b.w);
    return o.u;
}

// NOTE (round-9 lesson, measured): do NOT use nontemporal stores for the
// scattered u16/f32 epilogue stores -- L2's write-coalescing merges partial
// 64B lines and halves HBM write traffic (NT doubled WRITE_SIZE 34.9->67 MB
// and cost +36 us on gemm8p<1>). Plain cached stores everywhere.
// NOTE (round-11 lesson, measured): staging placement is regime-dependent.
// HBM-fetch-heavy EPI1: top-of-body staging (tail burst right after the
// barrier convoys with next-tile ds_reads: 87->103 us). L2-resident
// latency-bound EPI2: tail staging + 2-tile prologue prefetch helps (~-20 us).

// async global->LDS, 16 B per lane; LDS dest = wave-uniform base + lane*16
__device__ __forceinline__ void gload16(const u16* g, const u16* l) {
    __builtin_amdgcn_global_load_lds(
        (const __attribute__((address_space(1))) void*)g,
        (__attribute__((address_space(3))) void*)l, 16, 0, 0);
}

// ---------------- small kernels ----------------

__global__ void __launch_bounds__(64) zero_ss(float* ss) {
    if (threadIdx.x < 2) ss[threadIdx.x] = 0.f;
}

// ---------------- fused prep kernel ----------------
// One dispatch: twvh + sumsq x2 + cvt q + cvt Wq (+ cvt v). blockIdx.x ranges:
//   [0, 1536)      twvh v2: wvh[h][c][k] = bf16(hm[h,k]*Wv[k,c]), 64k x 32c tile,
//                  k-PAIRED u32 stores (wave = 128 B contiguous).
//   [1536, 2048)   sumsq: ss[0] += |Wv|^2 (256 blks), ss[1] += |Wq|^2 (256)
//   [2048, 3072)   cvt q  -> qb   (2,097,152 floats, exact)
//   [3072, 4608)   cvt Wq -> wqb  (3,145,728 floats, exact)
//   [4608, 6656)   cvt v  -> vb   (16,777,216 floats, 4-iter stride) [fullfat]
__global__ void __launch_bounds__(256)
prep_k(const float* __restrict__ Wv, const float* __restrict__ Wq,
       const float* __restrict__ q, const float* __restrict__ v,
       const float* __restrict__ hm, float* __restrict__ ss,
       u16* __restrict__ wvh, u16* __restrict__ qb,
       u16* __restrict__ wqb, u16* __restrict__ vb) {
    const int bid = blockIdx.x, tid = threadIdx.x;
    if (bid < 1536) {
        // ---- twvh v2: 64k x 32c tile, transpose + 8-head scale ----
        __shared__ float t[64][33];
        int bx = bid & 31, by = bid >> 5;        // 32 c-tiles x 48 k-tiles
        int cx0 = bx * 32, ky0 = by * 64;
        int tx = tid & 31, ty = tid >> 5;
#pragma unroll
        for (int j = ty; j < 64; j += 8)
            t[j][tx] = Wv[(size_t)(ky0 + j) * 1024 + cx0 + tx];
        // hv for this thread's k-pair (2tx, 2tx+1)
        int k0 = ky0 + 2 * tx;
        float hv0[8], hv1[8];
#pragma unroll
        for (int h = 0; h < 8; h++) {
            hv0[h] = hm[(size_t)h * 3072 + k0];
            hv1[h] = hm[(size_t)h * 3072 + k0 + 1];
        }
        __syncthreads();
#pragma unroll
        for (int j = ty; j < 32; j += 8) {
            float w0 = t[2 * tx][j], w1 = t[2 * tx + 1][j];
            int c = cx0 + j;
#pragma unroll
            for (int h = 0; h < 8; h++) {
                u32 val = (u32)f2b(hv0[h] * w0) | ((u32)f2b(hv1[h] * w1) << 16);
                *(u32*)(wvh + (size_t)h * 3145728 + (size_t)c * 3072 + k0) = val;
            }
        }
    } else if (bid < 2048) {
        // ---- sumsq of Wv (sub<256) / Wq ----
        int sub = bid - 1536;
        const float* W = (sub < 256) ? Wv : Wq;
        int lb = sub & 255;
        float acc = 0.f;
        const size_t stride = (size_t)256 * 256 * 8;
        for (size_t i = ((size_t)lb * 256 + tid) * 8; i < (size_t)(3072 * 1024); i += stride) {
            float4 a = *(const float4*)(W + i);
            float4 b = *(const float4*)(W + i + 4);
            acc += a.x * a.x + a.y * a.y + a.z * a.z + a.w * a.w;
            acc += b.x * b.x + b.y * b.y + b.z * b.z + b.w * b.w;
        }
#pragma unroll
        for (int o = 32; o > 0; o >>= 1) acc += __shfl_down(acc, o, 64);
        __shared__ float red[4];
        int lane = tid & 63, w6 = tid >> 6;
        if (lane == 0) red[w6] = acc;
        __syncthreads();
        if (tid == 0) atomicAdd(&ss[sub >> 8], red[0] + red[1] + red[2] + red[3]);
    } else if (bid < 3072) {
        // ---- cvt q -> qb (exact cover) ----
        size_t i = ((size_t)(bid - 2048) * 256 + tid) * 8;
        float4 a = *(const float4*)(q + i);
        float4 b = *(const float4*)(q + i + 4);
        *(uint4*)(qb + i) = cvt8(a, b);
    } else if (bid < 4608) {
        // ---- cvt Wq -> wqb (exact cover) ----
        size_t i = ((size_t)(bid - 3072) * 256 + tid) * 8;
        float4 a = *(const float4*)(Wq + i);
        float4 b = *(const float4*)(Wq + i + 4);
        *(uint4*)(wqb + i) = cvt8(a, b);
    } else {
        // ---- cvt v -> vb (grid-stride, 4 iters) ----
        const size_t stride = (size_t)2048 * 256 * 8;
        for (size_t i = ((size_t)(bid - 4608) * 256 + tid) * 8; i < (size_t)16777216; i += stride) {
            float4 a = *(const float4*)(v + i);
            float4 b = *(const float4*)(v + i + 4);
            *(uint4*)(vb + i) = cvt8(a, b);
        }
    }
}

// cb[o] = sum_k bv[k]*hm[h,k]*q_[b*128+d, k], o = b*1024 + h*128 + d.
// 256 blocks; 4 threads per output (K/4 each); shfl_xor quad-reduce; no atomics.
__global__ void __launch_bounds__(256) const_k(const u16* __restrict__ qbuf,
                                               const float* __restrict__ bv,
                                               const float* __restrict__ hm,
                                               float* __restrict__ cb) {
    int o = blockIdx.x * 64 + (threadIdx.x >> 2);   // 0..16383
    int qt = threadIdx.x & 3;                        // K quarter
    int b = o >> 10, hd = o & 1023, h = hd >> 7, d = hd & 127;
    const u16* qr = qbuf + ((size_t)b * 128 + d) * 3072 + qt * 768;
    const float* hr = hm + (size_t)h * 3072 + qt * 768;
    const float* br = bv + qt * 768;
    float acc = 0.f;
    for (int k = 0; k < 768; k += 8) {
        U8 uq; uq.u = *(const uint4*)(qr + k);
        float4 h0 = *(const float4*)(hr + k);
        float4 h1 = *(const float4*)(hr + k + 4);
        float4 b0 = *(const float4*)(br + k);
        float4 b1 = *(const float4*)(br + k + 4);
        acc += b2f(uq.s[0]) * h0.x * b0.x + b2f(uq.s[1]) * h0.y * b0.y +
               b2f(uq.s[2]) * h0.z * b0.z + b2f(uq.s[3]) * h0.w * b0.w +
               b2f(uq.s[4]) * h1.x * b1.x + b2f(uq.s[5]) * h1.y * b1.y +
               b2f(uq.s[6]) * h1.z * b1.z + b2f(uq.s[7]) * h1.w * b1.w;
    }
    acc += __shfl_xor(acc, 1, 64);
    acc += __shfl_xor(acc, 2, 64);
    if (qt == 0) cb[o] = acc;
}

// ---------------- legacy 128x128 BT-GEMM (2-phase, __syncthreads) ----------------
// kept for EPI 0 (small N, more blocks) and the fp32-A fallback of EPI 2.
// EPI 0: bijective XCD chunking -- grid (24,16), 48 blocks/XCD as 6bx x 8by;
// per-XCD operand footprint 3.5 MB < 4 MB L2.
template <int EPI, bool A_BF16>
__global__ void __launch_bounds__(256)
gemm_bt(const void* __restrict__ Ap, const u16* __restrict__ Bp, void* __restrict__ C,
        const float* __restrict__ ss, int ss_idx, const float* __restrict__ g,
        const float* __restrict__ bias, const float* __restrict__ cb,
        const float* __restrict__ hbias, int kdim, size_t abatch, size_t bbatch) {
    constexpr int BK = 32;
    __shared__ __align__(16) u16 sA[2][128 * BK];
    __shared__ __align__(16) u16 sB[2][128 * BK];

    const int tid = threadIdx.x;
    const int lane = tid & 63, wv = tid >> 6;
    const int wm = (wv & 1) * 64, wn = (wv >> 1) * 64;
    const int lr = lane & 15, quad = lane >> 4;
    const int z = blockIdx.z;

    int bxx, byy;
    if constexpr (EPI == 0) {
        int lin = blockIdx.y * 24 + blockIdx.x;     // grid (24,16)
        int xcd = lin & 7, i = lin >> 3;            // i in 0..47
        bxx = (xcd & 3) * 6 + i % 6;
        byy = (xcd >> 2) * 8 + i / 6;
    } else {
        bxx = blockIdx.x; byy = blockIdx.y;
    }
    const int arow0 = byy * 128;
    const int bcol0 = bxx * 128;

    const size_t aoff = (size_t)z * abatch;
    const size_t boff = (size_t)z * bbatch;

    const int srow = 16 * wv + (lane >> 2);
    const int qcg  = (lane & 3) ^ ((lane >> 3) & 3);
    const int lb0  = wv * 512;
    const int lb1  = lb0 + 2048;

    const u16* gB0 = Bp + boff + (size_t)(bcol0 + srow) * kdim + qcg * 8;
    const u16* gB1 = gB0 + (size_t)64 * kdim;

    const int r0 = tid >> 2, c0 = (tid & 3) * 8;
    const int w0 = r0 * 32 + (((tid & 3) ^ ((tid >> 3) & 3)) * 8);
    const int w1 = w0 + 2048;

    const u16* gA0 = nullptr; const u16* gA1 = nullptr;
    const float* fA0 = nullptr; const float* fA1 = nullptr;
    if constexpr (A_BF16) {
        gA0 = (const u16*)Ap + aoff + (size_t)(arow0 + srow) * kdim + qcg * 8;
        gA1 = gA0 + (size_t)64 * kdim;
    } else {
        fA0 = (const float*)Ap + aoff + (size_t)(arow0 + r0) * kdim + c0;
        fA1 = fA0 + (size_t)64 * kdim;
    }

    const int rsw = (quad ^ ((lr >> 1) & 3)) * 8;

    if constexpr (A_BF16) {
        gload16(gA0, sA[0] + lb0);
        gload16(gA1, sA[0] + lb1);
        gA0 += BK; gA1 += BK;
    } else {
        float4 x0 = *(const float4*)fA0, x1 = *(const float4*)(fA0 + 4);
        float4 y0 = *(const float4*)fA1, y1 = *(const float4*)(fA1 + 4);
        *(uint4*)(sA[0] + w0) = cvt8(x0, x1);
        *(uint4*)(sA[0] + w1) = cvt8(y0, y1);
        fA0 += BK; fA1 += BK;
    }
    gload16(gB0, sB[0] + lb0);
    gload16(gB1, sB[0] + lb1);
    gB0 += BK; gB1 += BK;

    f32x4 acc[4][4];
#pragma unroll
    for (int im = 0; im < 4; im++)
#pragma unroll
        for (int in = 0; in < 4; in++) acc[im][in] = (f32x4){0.f, 0.f, 0.f, 0.f};

    __syncthreads();

    int p = 0;
    for (int kt = 0; kt < kdim; kt += BK) {
        const bool more = (kt + BK < kdim);

        float4 ax0, ax1, ay0, ay1;
        if (more) {
            if constexpr (A_BF16) {
                gload16(gA0, sA[p ^ 1] + lb0);
                gload16(gA1, sA[p ^ 1] + lb1);
                gA0 += BK; gA1 += BK;
            } else {
                ax0 = *(const float4*)fA0; ax1 = *(const float4*)(fA0 + 4);
                ay0 = *(const float4*)fA1; ay1 = *(const float4*)(fA1 + 4);
                fA0 += BK; fA1 += BK;
            }
            gload16(gB0, sB[p ^ 1] + lb0);
            gload16(gB1, sB[p ^ 1] + lb1);
            gB0 += BK; gB1 += BK;
        }

        const u16* sAp = sA[p];
        const u16* sBp = sB[p];
        bf16x8 af[4], bfr[4];
#pragma unroll
        for (int im = 0; im < 4; im++)
            af[im] = *(const bf16x8*)(sAp + (wm + im * 16 + lr) * 32 + rsw);
#pragma unroll
        for (int in = 0; in < 4; in++)
            bfr[in] = *(const bf16x8*)(sBp + (wn + in * 16 + lr) * 32 + rsw);
#pragma unroll
        for (int im = 0; im < 4; im++)
#pragma unroll
            for (int in = 0; in < 4; in++)
                acc[im][in] = __builtin_amdgcn_mfma_f32_16x16x32_bf16(af[im], bfr[in], acc[im][in], 0, 0, 0);

        if (more) {
            if constexpr (!A_BF16) {
                u16* dA = sA[p ^ 1];
                *(uint4*)(dA + w0) = cvt8(ax0, ax1);
                *(uint4*)(dA + w1) = cvt8(ay0, ay1);
            }
        }
        __syncthreads();
        p ^= 1;
    }

    float scale = 1.f;
    if constexpr (EPI == 0 || EPI == 2) scale = g[0] / sqrtf(ss[ss_idx]);

#pragma unroll
    for (int im = 0; im < 4; im++) {
#pragma unroll
        for (int in = 0; in < 4; in++) {
#pragma unroll
            for (int reg = 0; reg < 4; reg++) {
                int gr = arow0 + wm + im * 16 + quad * 4 + reg;
                int gc = bcol0 + wn + in * 16 + lr;
                float val = acc[im][in][reg];
                if constexpr (EPI == 0) {
                    ((u16*)C)[(size_t)gr * 3072 + gc] = f2b(val * scale + bias[gc]);
                } else if constexpr (EPI == 1) {
                    size_t idx = (((size_t)(gr >> 7) * 8 + (gc >> 10)) * 128 + (gr & 127)) * 1024
                               + (gc & 1023);
                    ((u16*)C)[idx] = f2b(val);
                } else {
                    int h = gc >> 7, d = gc & 127;
                    float o = val * scale + cb[(size_t)z * 1024 + gc] + hbias[h];
                    ((float*)C)[(((size_t)z * 8 + h) * 1024 + gr) * 128 + d] = o;
                }
            }
        }
    }
}

// ---------------- 256x256 BT-GEMM, single-barrier-per-tile free-running pipeline --------
// ROUND-12: staging placement split by regime (round-11 counters):
//   EPI1 (HBM-fetch-heavy): TOP-OF-BODY staging (round-10 schedule, proven
//     87 us / MfmaUtil 51%). Tail-staging convoyed the load burst with
//     next-tile ds_reads after the barrier: 87 -> 103 us.
//   EPI2 (L2-resident, latency-bound, NT=16): TAIL staging + 2-tile prologue
//     prefetch (round-11 schedule, ~-20 us vs round-10).
// Hazard ledgers for both variants are proven in their source rounds.
// EPI 2: z-locality XCD chunking (XCD k owns z in {k, k+8}).
// Epilogue stores are PLAIN cached stores (round-9 NT regression: +36 us).
template <int EPI>
__global__ void __launch_bounds__(512, 2)
gemm8p(const u16* __restrict__ Ap, const u16* __restrict__ Bp, void* __restrict__ C,
       const float* __restrict__ ss, const float* __restrict__ g,
       const float* __restrict__ cb, const float* __restrict__ hbias,
       int kdim, size_t abatch, size_t bbatch) {
    constexpr bool TAIL = (EPI == 2);   // tail-staging only for the L2-resident GEMM
    __shared__ __align__(16) u16 sAb[2][256 * 64];
    __shared__ __align__(16) u16 sBb[2][256 * 64];

    const int tid = threadIdx.x;
    const int lane = tid & 63, wv = tid >> 6;
    const int wm = (wv & 1) * 128;            // M warp offset (2 warps)
    const int wn = (wv >> 1) * 64;            // N warp offset (4 warps)
    const int lr = lane & 15, quad = lane >> 4;

    int bx, by, z;
    if constexpr (EPI == 1) {
        // T1 chunked XCD swizzle: XCD k owns bx in [4k,4k+4), by 0..7
        int orig = blockIdx.y * 32 + blockIdx.x;       // gridDim = (32,8)
        int xcd = orig & 7, idx = orig >> 3;
        bx = (xcd << 2) | (idx & 3);
        by = idx >> 2;
        z = 0;
    } else {
        // z-locality: grid (4,4,16) -> XCD k runs z=k then z=k+8
        int lin = (blockIdx.z * 4 + blockIdx.y) * 4 + blockIdx.x;  // 0..255
        int xcd = lin & 7, i = lin >> 3;                           // i in 0..31
        z = xcd + 8 * (i >> 4);
        int sub = i & 15;
        bx = sub & 3; by = sub >> 2;
    }
    const int arow0 = by * 256, bcol0 = bx * 256;

    const size_t aoff = (size_t)z * abatch, boff = (size_t)z * bbatch;

    // staging lane map: call = 64 rows x 64 cols (8KB); thread covers row tid>>3,
    // 16B-group tid&7, fetching pre-swizzled global group (tid&7) ^ (row&7)
    const int sg = (tid & 7) ^ ((tid >> 3) & 7);
    const u16* gA = Ap + aoff + (size_t)(arow0 + (tid >> 3)) * kdim + sg * 8;
    const u16* gB = Bp + boff + (size_t)(bcol0 + (tid >> 3)) * kdim + sg * 8;
    const size_t ldk64 = (size_t)64 * kdim;    // 64-row call stride (elements)
    const int ldst = wv * 512;                 // wave's u16 offset within a call

    // frag read bases (u16): row*64 + slot*8, slot = quad ^ (row&7); ks=1 -> ^32
    const int slot = (quad ^ (lane & 7)) * 8;
    const int rbA = (wm + lr) * 64 + slot;
    const int rbB = (wn + lr) * 64 + slot;

    f32x4 acc[8][4];
#pragma unroll
    for (int im = 0; im < 8; im++)
#pragma unroll
        for (int in = 0; in < 4; in++) acc[im][in] = (f32x4){0.f, 0.f, 0.f, 0.f};

    // ---- prologue ----
    gload16(gB + 0 * ldk64, sBb[0] + 0 * 4096 + ldst);
    gload16(gB + 1 * ldk64, sBb[0] + 1 * 4096 + ldst);
    gload16(gB + 2 * ldk64, sBb[0] + 2 * 4096 + ldst);
    gload16(gB + 3 * ldk64, sBb[0] + 3 * 4096 + ldst);
    gload16(gA + 0 * ldk64, sAb[0] + 0 * 4096 + ldst);
    gload16(gA + 1 * ldk64, sAb[0] + 1 * 4096 + ldst);
    gload16(gA + 2 * ldk64, sAb[0] + 2 * 4096 + ldst);
    gload16(gA + 3 * ldk64, sAb[0] + 3 * 4096 + ldst);
    if constexpr (TAIL) {
        // also stage tile 1 -> P1; drain only tile 0 (tile 1 flies under body 0)
        gload16(gB + 64 + 0 * ldk64, sBb[1] + 0 * 4096 + ldst);
        gload16(gB + 64 + 1 * ldk64, sBb[1] + 1 * 4096 + ldst);
        gload16(gB + 64 + 2 * ldk64, sBb[1] + 2 * 4096 + ldst);
        gload16(gB + 64 + 3 * ldk64, sBb[1] + 3 * 4096 + ldst);
        gload16(gA + 64 + 0 * ldk64, sAb[1] + 0 * 4096 + ldst);
        gload16(gA + 64 + 1 * ldk64, sAb[1] + 1 * 4096 + ldst);
        gload16(gA + 64 + 2 * ldk64, sAb[1] + 2 * 4096 + ldst);
        gload16(gA + 64 + 3 * ldk64, sAb[1] + 3 * 4096 + ldst);
        gA += 128; gB += 128;                  // -> K-tile 2 columns
        asm volatile("s_waitcnt vmcnt(8)" ::: "memory");
    } else {
        gA += 64; gB += 64;                    // -> K-tile 1 columns
        asm volatile("s_waitcnt vmcnt(0)" ::: "memory");
    }
    __builtin_amdgcn_s_barrier();

    const u16* sAd = sAb[0];
    const u16* sBd = sBb[0];
    u16* dA = (u16*)sAb[1];
    u16* dB = (u16*)sBb[1];

    bf16x8 af[4], bfr[4], af1[4], af2[4], bf2[4], af3[4];
    // Q0 frags for tile 0
#pragma unroll
    for (int n = 0; n < 4; n++) bfr[n] = *(const bf16x8*)(sBd + rbB + n * 1024);
#pragma unroll
    for (int j = 0; j < 4; j++) af[j] = *(const bf16x8*)(sAd + rbA + j * 1024);

    const int NT = kdim >> 6;
    for (int t = 0; t < NT; ++t) {
        // ---- top-of-body staging (EPI1 path): stage(t+1) -> D ----
        if constexpr (!TAIL) {
            if (t + 1 < NT) {
                gload16(gB + 0 * ldk64, dB + 0 * 4096 + ldst);
                gload16(gB + 1 * ldk64, dB + 1 * 4096 + ldst);
                gload16(gB + 2 * ldk64, dB + 2 * 4096 + ldst);
                gload16(gB + 3 * ldk64, dB + 3 * 4096 + ldst);
                gload16(gA + 0 * ldk64, dA + 0 * 4096 + ldst);
                gload16(gA + 1 * ldk64, dA + 1 * 4096 + ldst);
                gload16(gA + 2 * ldk64, dA + 2 * 4096 + ldst);
                gload16(gA + 3 * ldk64, dA + 3 * 4096 + ldst);
            }
        }

        // ---- read Q1, MFMA Q0 ----
#pragma unroll
        for (int j = 0; j < 4; j++) af1[j] = *(const bf16x8*)(sAd + rbA + (4 + j) * 1024);
        __builtin_amdgcn_s_setprio(1);
#pragma unroll
        for (int j = 0; j < 4; j++)
#pragma unroll
            for (int n = 0; n < 4; n++)
                acc[j][n] = __builtin_amdgcn_mfma_f32_16x16x32_bf16(af[j], bfr[n], acc[j][n], 0, 0, 0);
        __builtin_amdgcn_s_setprio(0);

        // ---- read Q2, MFMA Q1 ----
#pragma unroll
        for (int n = 0; n < 4; n++) bf2[n] = *(const bf16x8*)(sBd + (rbB ^ 32) + n * 1024);
#pragma unroll
        for (int j = 0; j < 4; j++) af2[j] = *(const bf16x8*)(sAd + (rbA ^ 32) + j * 1024);
        __builtin_amdgcn_s_setprio(1);
#pragma unroll
        for (int j = 0; j < 4; j++)
#pragma unroll
            for (int n = 0; n < 4; n++)
                acc[4 + j][n] = __builtin_amdgcn_mfma_f32_16x16x32_bf16(af1[j], bfr[n], acc[4 + j][n], 0, 0, 0);
        __builtin_amdgcn_s_setprio(0);

        // ---- read Q3, MFMA Q2 ----
#pragma unroll
        for (int j = 0; j < 4; j++) af3[j] = *(const bf16x8*)(sAd + (rbA ^ 32) + (4 + j) * 1024);
        __builtin_amdgcn_s_setprio(1);
#pragma unroll
        for (int j = 0; j < 4; j++)
#pragma unroll
            for (int n = 0; n < 4; n++)
                acc[j][n] = __builtin_amdgcn_mfma_f32_16x16x32_bf16(af2[j], bf2[n], acc[j][n], 0, 0, 0);
        __builtin_amdgcn_s_setprio(0);

        // ---- tile-end sync (the only barrier) ----
        asm volatile("s_waitcnt vmcnt(0)" ::: "memory");   // next tile staged
        asm volatile("s_waitcnt lgkmcnt(0)" ::: "memory"); // my reads of P[t&1] done
        __builtin_amdgcn_s_barrier();

        // ---- tail ----
        if constexpr (TAIL) {
            // stage(t+2) -> P[t&1] (dead until t+2); drained at end of body(t+1)
            if (t + 2 < NT) {
                u16* tA = (u16*)sAd;
                u16* tB = (u16*)sBd;
                gload16(gB + 0 * ldk64, tB + 0 * 4096 + ldst);
                gload16(gB + 1 * ldk64, tB + 1 * 4096 + ldst);
                gload16(gB + 2 * ldk64, tB + 2 * 4096 + ldst);
                gload16(gB + 3 * ldk64, tB + 3 * 4096 + ldst);
                gload16(gA + 0 * ldk64, tA + 0 * 4096 + ldst);
                gload16(gA + 1 * ldk64, tA + 1 * 4096 + ldst);
                gload16(gA + 2 * ldk64, tA + 2 * 4096 + ldst);
                gload16(gA + 3 * ldk64, tA + 3 * 4096 + ldst);
            }
        }
        if (t + 1 < NT) {
#pragma unroll
            for (int n = 0; n < 4; n++) bfr[n] = *(const bf16x8*)(dB + rbB + n * 1024);
#pragma unroll
            for (int j = 0; j < 4; j++) af[j] = *(const bf16x8*)(dA + rbA + j * 1024);
        }
        __builtin_amdgcn_s_setprio(1);
#pragma unroll
        for (int j = 0; j < 4; j++)
#pragma unroll
            for (int n = 0; n < 4; n++)
                acc[4 + j][n] = __builtin_amdgcn_mfma_f32_16x16x32_bf16(af3[j], bf2[n], acc[4 + j][n], 0, 0, 0);
        __builtin_amdgcn_s_setprio(0);

        // swap dbufs, advance K
        const u16* tp = sAd; sAd = dA; dA = (u16*)tp;
        tp = sBd; sBd = dB; dB = (u16*)tp;
        gA += 64; gB += 64;
    }

    // ---- epilogue ----
    float scale = 1.f;
    if constexpr (EPI == 2) scale = g[0] / sqrtf(ss[0]);

#pragma unroll
    for (int im = 0; im < 8; im++) {
#pragma unroll
        for (int in = 0; in < 4; in++) {
#pragma unroll
            for (int reg = 0; reg < 4; reg++) {
                int gr = arow0 + wm + im * 16 + quad * 4 + reg;  // row (M)
                int gc = bcol0 + wn + in * 16 + lr;              // col (N)
                float val = acc[im][in][reg];
                if constexpr (EPI == 1) {
                    // gr = b*128+d (M=2048), gc = h*1024+c (N=8192) -> tbuf[b][h][d][c]
                    size_t idx = (((size_t)(gr >> 7) * 8 + (gc >> 10)) * 128 + (gr & 127)) * 1024
                               + (gc & 1023);
                    ((u16*)C)[idx] = f2b(val);
                } else {
                    int h = gc >> 7, d = gc & 127;
                    float o = val * scale + cb[(size_t)z * 1024 + gc] + hbias[h];
                    ((float*)C)[(((size_t)z * 8 + h) * 1024 + gr) * 128 + d] = o;
                }
            }
        }
    }
}

// ---------------- launch ----------------

extern "C" void kernel_launch(void* const* d_in, const int* in_sizes, int n_in,
                              void* d_out, int out_size, void* d_ws, size_t ws_size,
                              hipStream_t stream) {
    (void)in_sizes; (void)n_in; (void)out_size;
    const float* v  = (const float*)d_in[0];   // (16,1024,1024) fp32
    const float* q  = (const float*)d_in[1];   // (16,128,1024)  fp32
    const float* Wv = (const float*)d_in[2];   // (3072,1024)    fp32
    const float* gv = (const float*)d_in[3];
    const float* bv = (const float*)d_in[4];   // (3072)
    const float* Wq = (const float*)d_in[5];   // (3072,1024)
    const float* gq = (const float*)d_in[6];
    const float* bq = (const float*)d_in[7];   // (3072)
    const float* hm = (const float*)d_in[8];   // (8,3072)
    const float* hb = (const float*)d_in[9];   // (8)
    float* out = (float*)d_out;                // fp32 output (16,8,1024,128) = 67 MB

    // workspace layout (floor 46.2 MB; +33.5 MB vb if available)
    char* ws = (char*)d_ws;
    float* ss   = (float*)ws;                          // 256 B
    float* cb   = (float*)(ws + 256);                  // 64 KB
    u16*   qbuf = (u16*)(ws + 256 + 65536);            // 2048*3072 bf16 = 12 MB
    u16*   tbuf = (u16*)(ws + 256 + 65536 + 12582912); // 16*8*128*1024 bf16 = 33.5 MB
    u16*   vb   = (u16*)(ws + 256 + 65536 + 12582912 + 33554432);  // optional 33.5 MB
    const size_t need_vb = 256 + 65536 + 12582912 + 33554432 + 33554432;  // ~80.2 MB
    const bool fullfat = (ws_size >= need_vb);

    // scratch in d_out (67.1 MB), all dead before the final gemm writes out:
    //   wvh 8*1024*3072 bf16 = 50.33 MB | qb 2048*1024 bf16 = 4.19 MB | wqb 3072*1024 bf16 = 6.29 MB
    u16* wvh = (u16*)d_out;
    u16* qb  = (u16*)((char*)d_out + 50331648);
    u16* wqb = (u16*)((char*)d_out + 54525952);   // ends at 60.8 MB < 67.1 MB

    zero_ss<<<1, 64, 0, stream>>>(ss);

    // fused prep: twvh + sumsq + cvt q + cvt Wq (+ cvt v when fullfat)
    prep_k<<<fullfat ? 6656 : 4608, 256, 0, stream>>>(
        Wv, Wq, q, v, hm, ss, wvh, qb, wqb, vb);

    // q_ = q * wn(Wq)^T + bq   (2048 x 3072)
    gemm_bt<0, true><<<dim3(24, 16, 1), 256, 0, stream>>>(
        qb, wqb, qbuf, ss, 1, gq, bq, nullptr, nullptr, 1024, 0, 0);

    // cb[b,hd] = sum_k bv*hm*q_
    const_k<<<256, 256, 0, stream>>>(qbuf, bv, hm, cb);

    // T[b,h,d,c] = sum_k q_[b,d,k] * wvh[h,c,k]  -- ONE GEMM: M=2048, N=8192, K=3072
    gemm8p<1><<<dim3(32, 8, 1), 512, 0, stream>>>(
        qbuf, wvh, tbuf, nullptr, nullptr, nullptr, nullptr, 3072, 0, 0);

    // logits[b,h,n,d] = scale_v * sum_c v[b,n,c]*T[b,hd,c] + cb[b,hd] + hbias[h]
    if (fullfat) {
        gemm8p<2><<<dim3(4, 4, 16), 512, 0, stream>>>(
            vb, tbuf, out, ss, gv, cb, hb, 1024, 1048576, 1048576);
    } else {
        gemm_bt<2, false><<<dim3(8, 8, 16), 256, 0, stream>>>(
            v, tbuf, out, ss, 0, gv, nullptr, cb, hb, 1024, 1048576, 1048576);
    }
}